// Round 12
// baseline (1335.786 us; speedup 1.0000x reference)
//
#include <hip/hip_runtime.h>
#include <math.h>

#define Nn 50000
#define Ee 1600000
#define Bb 512
#define TE 64
#define NTILES (Ee / TE)
#define NB ((Nn + 255) / 256)

typedef __bf16 bf16;
typedef __bf16 bf16x8 __attribute__((ext_vector_type(8)));
typedef __bf16 bf16x4 __attribute__((ext_vector_type(4)));
typedef float f32x4 __attribute__((ext_vector_type(4)));

__device__ __forceinline__ float silu_f(float v) {
    return v * __builtin_amdgcn_rcpf(1.f + __expf(-v));
}
__device__ __forceinline__ float tanh_f(float x) {
    float e = __expf(2.f * x);
    return 1.f - 2.f * __builtin_amdgcn_rcpf(e + 1.f);
}
__device__ __forceinline__ int pack2bf(float a, float b) {
    unsigned short ua = __builtin_bit_cast(unsigned short, (bf16)a);
    unsigned short ub = __builtin_bit_cast(unsigned short, (bf16)b);
    return (int)ua | ((int)ub << 16);
}
__device__ __forceinline__ float unlo(int v) {
    return __builtin_bit_cast(float, v << 16);
}
__device__ __forceinline__ float unhi(int v) {
    return __builtin_bit_cast(float, v & 0xffff0000);
}

// ---------------- weight packing into MFMA A-fragment order ----------------
__device__ __forceinline__ void packfrag(bf16* dst, const float* src, int idx) {
    int j = idx & 7, lane = (idx >> 3) & 63, gT = idx >> 9;
    int kc = gT >> 2, T = gT & 3;
    int k = kc * 32 + (lane >> 4) * 8 + j;
    int n = T * 16 + (lane & 15);
    dst[idx] = (bf16)src[k * 64 + n];
}

// fused setup: h=emb[z] (fp32+bf16), weight packing, degree histogram (independent jobs)
#define SETUP_TOT (Nn * 64 + 102400 + Ee)
__global__ void k_setup(float* __restrict__ h, bf16* __restrict__ hb,
                        const int* __restrict__ z, const float* __restrict__ emb,
                        const float* __restrict__ eW1, const float* __restrict__ eW2,
                        const float* __restrict__ nW1, const float* __restrict__ nW2,
                        const float* __restrict__ qW1,
                        bf16* __restrict__ pw1, bf16* __restrict__ pw2,
                        bf16* __restrict__ pn1, bf16* __restrict__ pn2,
                        bf16* __restrict__ pq1,
                        const int* __restrict__ rows, int* __restrict__ deg) {
    for (int i = blockIdx.x * blockDim.x + threadIdx.x; i < SETUP_TOT;
         i += gridDim.x * blockDim.x) {
        if (i < Nn * 64) {
            int n = i >> 6, f = i & 63;
            float v = emb[z[n] * 64 + f];
            h[i] = v;
            hb[i] = (bf16)v;
        } else if (i < Nn * 64 + 102400) {
            int tid = i - Nn * 64;
            if (tid < 32768) {
                int l = tid >> 13, idx = tid & 8191;
                packfrag(pw1 + l * 8192, eW1 + (size_t)l * 129 * 64, idx);
            } else if (tid < 49152) {
                int k = tid - 32768, l = k >> 12, idx = k & 4095;
                packfrag(pw2 + l * 4096, eW2 + (size_t)l * 4096, idx);
            } else if (tid < 81920) {
                int k = tid - 49152, l = k >> 13, idx = k & 8191;
                packfrag(pn1 + l * 8192, nW1 + (size_t)l * 8192, idx);
            } else if (tid < 98304) {
                int k = tid - 81920, l = k >> 12, idx = k & 4095;
                packfrag(pn2 + l * 4096, nW2 + (size_t)l * 4096, idx);
            } else {
                packfrag(pq1, qW1, tid - 98304);
            }
        } else {
            int e = i - Nn * 64 - 102400;
            atomicAdd(&deg[rows[e]], 1);
        }
    }
}

__global__ void k_scan1(const int* __restrict__ deg, int* __restrict__ bsum) {
    __shared__ int red[4];
    int b = blockIdx.x;
    int i = b * 256 + threadIdx.x;
    int v = (i < Nn) ? deg[i] : 0;
#pragma unroll
    for (int off = 1; off < 64; off <<= 1) v += __shfl_xor(v, off);
    if ((threadIdx.x & 63) == 0) red[threadIdx.x >> 6] = v;
    __syncthreads();
    if (threadIdx.x == 0) bsum[b] = red[0] + red[1] + red[2] + red[3];
}

__global__ void k_scan2(const int* __restrict__ bsum, int* __restrict__ boff) {
    __shared__ int s[256];
    int t = threadIdx.x;
    int v = (t < NB) ? bsum[t] : 0;
    s[t] = v;
    __syncthreads();
    for (int off = 1; off < 256; off <<= 1) {
        int u = (t >= off) ? s[t - off] : 0;
        __syncthreads();
        s[t] += u;
        __syncthreads();
    }
    if (t < NB) boff[t] = s[t] - v;
}

// fused: exclusive scan -> cur (scatter cursor) + rows_s expansion
__global__ void k_scan3(const int* __restrict__ deg, const int* __restrict__ boff,
                        int* __restrict__ cur, int* __restrict__ rows_s) {
    __shared__ int s[256];
    int b = blockIdx.x, t = threadIdx.x;
    int i = b * 256 + t;
    int v = (i < Nn) ? deg[i] : 0;
    s[t] = v;
    __syncthreads();
    for (int off = 1; off < 256; off <<= 1) {
        int u = (t >= off) ? s[t - off] : 0;
        __syncthreads();
        s[t] += u;
        __syncthreads();
    }
    if (i < Nn) {
        int en = boff[b] + s[t];
        int st = en - v;
        cur[i] = st;
        for (int o = st; o < en; ++o) rows_s[o] = i;
    }
}

// cols-only scatter; cur holds absolute offsets
__global__ void k_scatter(const int* __restrict__ rows, const int* __restrict__ cols,
                          int* __restrict__ cur, int* __restrict__ cols_s) {
    int e = blockIdx.x * blockDim.x + threadIdx.x;
    if (e < Ee) {
        int o = atomicAdd(&cur[rows[e]], 1);
        cols_s[o] = cols[e];
    }
}

// ---------------- layer-0 node projection: Pa = H@W1a + b1, Pb = H@W1b (bf16 out) ----------------
__global__ __launch_bounds__(256) void k_proj(
    const bf16* __restrict__ hbuf, const bf16* __restrict__ pw1l,
    const float* __restrict__ b1v,
    bf16* __restrict__ Pa, bf16* __restrict__ Pb) {
    __shared__ __align__(16) bf16 inB[8 * 64 * 8];
    __shared__ float dhT[64 * 65];
    __shared__ __align__(16) float sb1[64];

    const int t = threadIdx.x;
    const int l = t & 63, w = t >> 6, q = l >> 4, nl = l & 15;
    const int fq = 4 * q;
    const int ge = t >> 2, part = t & 3;

    bf16x8 w1f[4][4];
#pragma unroll
    for (int kc = 0; kc < 4; ++kc)
#pragma unroll
        for (int T = 0; T < 4; ++T)
            w1f[kc][T] = *(const bf16x8*)(pw1l + (((kc * 4 + T) * 64 + l) << 3));
    if (t < 64) sb1[t] = b1v[t];

    const int NT = (Nn + 63) / 64;
    for (int bt = blockIdx.x; bt < NT; bt += gridDim.x) {
        const int base = bt * 64;
        __syncthreads();
        {
            int n = base + ge;
            if (n < Nn) {
                const bf16* hr = hbuf + ((size_t)n << 6) + part * 16;
                *(bf16x8*)&inB[(((part * 2 + 0) * 64) + ge) << 3] = *(const bf16x8*)(hr);
                *(bf16x8*)&inB[(((part * 2 + 1) * 64) + ge) << 3] = *(const bf16x8*)(hr + 8);
            } else {
                bf16x8 zz = {(bf16)0.f, (bf16)0.f, (bf16)0.f, (bf16)0.f,
                             (bf16)0.f, (bf16)0.f, (bf16)0.f, (bf16)0.f};
                *(bf16x8*)&inB[(((part * 2 + 0) * 64) + ge) << 3] = zz;
                *(bf16x8*)&inB[(((part * 2 + 1) * 64) + ge) << 3] = zz;
            }
        }
        __syncthreads();

        f32x4 apa[4], apb[4];
#pragma unroll
        for (int T = 0; T < 4; ++T) {
            apa[T] = (f32x4){0.f, 0.f, 0.f, 0.f};
            apb[T] = (f32x4){0.f, 0.f, 0.f, 0.f};
        }
#pragma unroll
        for (int kc = 0; kc < 2; ++kc) {
            bf16x8 bfrag = *(const bf16x8*)&inB[(((kc * 4 + q) * 64) + w * 16 + nl) << 3];
#pragma unroll
            for (int T = 0; T < 4; ++T) {
                apa[T] = __builtin_amdgcn_mfma_f32_16x16x32_bf16(w1f[kc][T], bfrag, apa[T], 0, 0, 0);
                apb[T] = __builtin_amdgcn_mfma_f32_16x16x32_bf16(w1f[kc + 2][T], bfrag, apb[T], 0, 0, 0);
            }
        }
#pragma unroll
        for (int T = 0; T < 4; ++T) {
#pragma unroll
            for (int r = 0; r < 4; ++r)
                dhT[(T * 16 + fq + r) * 65 + w * 16 + nl] = apa[T][r] + sb1[T * 16 + fq + r];
        }
        __syncthreads();
        {
            int n = base + ge;
            if (n < Nn) {
#pragma unroll
                for (int j = 0; j < 4; ++j) {
                    int f = part * 16 + j * 4;
                    bf16x4 bv = {(bf16)dhT[(f + 0) * 65 + ge], (bf16)dhT[(f + 1) * 65 + ge],
                                 (bf16)dhT[(f + 2) * 65 + ge], (bf16)dhT[(f + 3) * 65 + ge]};
                    *(bf16x4*)(Pa + ((size_t)n << 6) + f) = bv;
                }
            }
        }
        __syncthreads();
#pragma unroll
        for (int T = 0; T < 4; ++T) {
#pragma unroll
            for (int r = 0; r < 4; ++r)
                dhT[(T * 16 + fq + r) * 65 + w * 16 + nl] = apb[T][r];
        }
        __syncthreads();
        {
            int n = base + ge;
            if (n < Nn) {
#pragma unroll
                for (int j = 0; j < 4; ++j) {
                    int f = part * 16 + j * 4;
                    bf16x4 bv = {(bf16)dhT[(f + 0) * 65 + ge], (bf16)dhT[(f + 1) * 65 + ge],
                                 (bf16)dhT[(f + 2) * 65 + ge], (bf16)dhT[(f + 3) * 65 + ge]};
                    *(bf16x4*)(Pb + ((size_t)n << 6) + f) = bv;
                }
            }
        }
    }
}

// ---------------- edge kernel: gather bf16 Pa/Pb, fragment-native layout ----------------
// Thread (w, q, nl) owns edge eo+nl and B-fragment k-slots {c2*32 + q*8 + j}.
// Tile mapping REVERTED to strided grid-stride (R4 swizzle experiment measured
// FETCH 139->158MB, dur 138->141: locality theory wrong; strided sweep is better).
// NEW: 2-stage software pipeline — next tile's rows/cols indices and Pa/Pb
// gathers are issued during the current tile's compute and carried in registers
// across the reduction barriers (T14 issue-early; hides idx->gather chain).
__global__ __launch_bounds__(256, 8) void k_edge(
    const int* __restrict__ rows_s, const int* __restrict__ cols_s,
    const bf16* __restrict__ Pa, const bf16* __restrict__ Pb,
    const float* __restrict__ x,
    const bf16* __restrict__ pw2l,
    const float* __restrict__ w1f32,
    const float* __restrict__ b2v,
    const float* __restrict__ cwv, const float* __restrict__ cbv,
    float* __restrict__ m_agg, float* __restrict__ x_acc) {
    __shared__ __align__(16) bf16 lw2[4096];
    __shared__ __align__(16) float w128s[64], b2s[64], cws[64];
    __shared__ int mEp[32 * 65];
    __shared__ __align__(16) float relsm[64 * 4];
    __shared__ float coefs[64];
    __shared__ int srow[64];

    const int t = threadIdx.x;
    const int l = t & 63, w = t >> 6, q = l >> 4, nl = l & 15;
    const int fq = 4 * q;

    {
        const int4* s2 = (const int4*)pw2l;
        int4* d2p = (int4*)lw2;
#pragma unroll
        for (int i = 0; i < 2; ++i) d2p[t + 256 * i] = s2[t + 256 * i];
        if (t < 64) {
            w128s[t] = w1f32[128 * 64 + t];
            b2s[t] = b2v[t];
            cws[t] = cwv[t];
        }
    }
    const float cb0 = cbv[0];
    __syncthreads();

    // tile-invariant dist2-weight quads for this thread's k-slots (hoisted)
    const float4 w00 = *(const float4*)&w128s[q * 8 + 0];
    const float4 w01 = *(const float4*)&w128s[q * 8 + 4];
    const float4 w10 = *(const float4*)&w128s[32 + q * 8 + 0];
    const float4 w11 = *(const float4*)&w128s[32 + q * 8 + 4];

    const int gs = gridDim.x;

    // pipeline prologue: indices + gathers for the first tile
    int r_g, c_g;
    int4 A0, A1, B0, B1;
    {
        const int eg = blockIdx.x * TE + w * 16 + nl;
        r_g = rows_s[eg];
        c_g = cols_s[eg];
        const bf16* par = Pa + ((size_t)r_g << 6) + q * 8;
        const bf16* pbc = Pb + ((size_t)c_g << 6) + q * 8;
        A0 = *(const int4*)(par);
        A1 = *(const int4*)(par + 32);
        B0 = *(const int4*)(pbc);
        B1 = *(const int4*)(pbc + 32);
    }

    for (int tile = blockIdx.x; tile < NTILES; tile += gs) {
        // current tile geometry (indices already in registers)
        float rx = x[r_g * 3 + 0] - x[c_g * 3 + 0];
        float ry = x[r_g * 3 + 1] - x[c_g * 3 + 1];
        float rz = x[r_g * 3 + 2] - x[c_g * 3 + 2];
        float d2 = fmaf(rx, rx, fmaf(ry, ry, rz * rz));
        if (q == 0) {
            srow[w * 16 + nl] = r_g;
            float4 rv;
            rv.x = rx; rv.y = ry; rv.z = rz; rv.w = d2;
            *(float4*)&relsm[(w * 16 + nl) * 4] = rv;
        }

        // prefetch next tile's indices (issue early; consumed below)
        const int nt = tile + gs;
        const int ntc = (nt < NTILES) ? nt : tile;
        const int eg2 = ntc * TE + w * 16 + nl;
        int r_n = rows_s[eg2];
        int c_n = cols_s[eg2];

        // silu + pack with current gathers (in registers since last iteration)
        union { int i[4]; bf16x8 v; } bu0, bu1;
        bu0.i[0] = pack2bf(silu_f(fmaf(w00.x, d2, unlo(A0.x) + unlo(B0.x))),
                           silu_f(fmaf(w00.y, d2, unhi(A0.x) + unhi(B0.x))));
        bu0.i[1] = pack2bf(silu_f(fmaf(w00.z, d2, unlo(A0.y) + unlo(B0.y))),
                           silu_f(fmaf(w00.w, d2, unhi(A0.y) + unhi(B0.y))));
        bu0.i[2] = pack2bf(silu_f(fmaf(w01.x, d2, unlo(A0.z) + unlo(B0.z))),
                           silu_f(fmaf(w01.y, d2, unhi(A0.z) + unhi(B0.z))));
        bu0.i[3] = pack2bf(silu_f(fmaf(w01.z, d2, unlo(A0.w) + unlo(B0.w))),
                           silu_f(fmaf(w01.w, d2, unhi(A0.w) + unhi(B0.w))));
        bu1.i[0] = pack2bf(silu_f(fmaf(w10.x, d2, unlo(A1.x) + unlo(B1.x))),
                           silu_f(fmaf(w10.y, d2, unhi(A1.x) + unhi(B1.x))));
        bu1.i[1] = pack2bf(silu_f(fmaf(w10.z, d2, unlo(A1.y) + unlo(B1.y))),
                           silu_f(fmaf(w10.w, d2, unhi(A1.y) + unhi(B1.y))));
        bu1.i[2] = pack2bf(silu_f(fmaf(w11.x, d2, unlo(A1.z) + unlo(B1.z))),
                           silu_f(fmaf(w11.y, d2, unhi(A1.z) + unhi(B1.z))));
        bu1.i[3] = pack2bf(silu_f(fmaf(w11.z, d2, unlo(A1.w) + unlo(B1.w))),
                           silu_f(fmaf(w11.w, d2, unhi(A1.w) + unhi(B1.w))));

        // prefetch next tile's Pa/Pb gathers; latency hides under MFMA+reduction
        {
            const bf16* parn = Pa + ((size_t)r_n << 6) + q * 8;
            const bf16* pbcn = Pb + ((size_t)c_n << 6) + q * 8;
            A0 = *(const int4*)(parn);
            A1 = *(const int4*)(parn + 32);
            B0 = *(const int4*)(pbcn);
            B1 = *(const int4*)(pbcn + 32);
        }

        f32x4 a2[4];
#pragma unroll
        for (int T = 0; T < 4; ++T) a2[T] = (f32x4){0.f, 0.f, 0.f, 0.f};
#pragma unroll
        for (int T = 0; T < 4; ++T) {
            bf16x8 wf = *(const bf16x8*)&lw2[(((0 * 4 + T) * 64) + l) << 3];
            a2[T] = __builtin_amdgcn_mfma_f32_16x16x32_bf16(wf, bu0.v, a2[T], 0, 0, 0);
        }
#pragma unroll
        for (int T = 0; T < 4; ++T) {
            bf16x8 wf = *(const bf16x8*)&lw2[(((1 * 4 + T) * 64) + l) << 3];
            a2[T] = __builtin_amdgcn_mfma_f32_16x16x32_bf16(wf, bu1.v, a2[T], 0, 0, 0);
        }
        float pc = 0.f;
#pragma unroll
        for (int T = 0; T < 4; ++T) {
            const float4 bq = *(const float4*)&b2s[T * 16 + fq];
            const float4 cq = *(const float4*)&cws[T * 16 + fq];
            float m0 = silu_f(a2[T][0] + bq.x);
            float m1 = silu_f(a2[T][1] + bq.y);
            float m2 = silu_f(a2[T][2] + bq.z);
            float m3 = silu_f(a2[T][3] + bq.w);
            int p0 = (T * 16 + fq) >> 1;
            mEp[(p0 + 0) * 65 + w * 16 + nl] = pack2bf(m0, m1);
            mEp[(p0 + 1) * 65 + w * 16 + nl] = pack2bf(m2, m3);
            pc += m0 * cq.x + m1 * cq.y + m2 * cq.z + m3 * cq.w;
        }
        pc += __shfl_xor(pc, 16);
        pc += __shfl_xor(pc, 32);
        if (q == 0) coefs[w * 16 + nl] = tanh_f(pc + cb0);
        __syncthreads();  // barrier A

        {
            int rl = srow[l];
            int rprev = __shfl(rl, l - 1);
            bool isst = (l == 0) || (rl != rprev);
            unsigned long long mask = __ballot(isst);
            const int pair = l & 31, half = l >> 5;
            unsigned long long mm = mask;
            int s = 0;
            while (mm) {
                int st = __ffsll(mm) - 1;
                mm &= mm - 1;
                if ((s & 3) == w) {
                    int en = mm ? (__ffsll(mm) - 1) : TE;
                    int row = __shfl(rl, st);
                    float s0 = 0.f, s1 = 0.f, sx = 0.f;
                    for (int e = st + half; e < en; e += 2) {
                        int pv = mEp[pair * 65 + e];
                        s0 += __builtin_bit_cast(float, pv << 16);
                        s1 += __builtin_bit_cast(float, pv & 0xffff0000);
                    }
                    if (half == 1 && pair < 3) {
                        for (int e = st; e < en; ++e)
                            sx += relsm[e * 4 + pair] * coefs[e];
                    }
                    s0 += __shfl_xor(s0, 32);
                    s1 += __shfl_xor(s1, 32);
                    if (half == 0) {
                        atomicAdd(m_agg + (size_t)row * 64 + 2 * pair, s0);
                        atomicAdd(m_agg + (size_t)row * 64 + 2 * pair + 1, s1);
                    } else if (pair < 3) {
                        atomicAdd(x_acc + (size_t)row * 3 + pair, sx);
                    }
                }
                s++;
            }
        }
        __syncthreads();  // barrier B

        // rotate pipeline registers
        r_g = r_n;
        c_g = c_n;
    }
}

// ---------------- node kernel (MFMA, grid-stride; fused next-layer projection; zeroes accumulators) ----------------
__global__ __launch_bounds__(256) void k_node(
    float* __restrict__ m_agg, float* __restrict__ x_acc,
    const bf16* __restrict__ pn1l, const bf16* __restrict__ pn2l,
    const float* __restrict__ b1v, const float* __restrict__ b2v,
    float* __restrict__ h, bf16* __restrict__ hbuf, float* __restrict__ x,
    const bf16* __restrict__ pw1n, const float* __restrict__ b1n,
    bf16* __restrict__ Pa, bf16* __restrict__ Pb, int donext) {
    __shared__ __align__(16) bf16 inB[16 * 64 * 8];
    __shared__ float dhT[64 * 65];
    __shared__ __align__(16) float sb1[64], sb2[64], sb1n[64];

    const int t = threadIdx.x;
    const int l = t & 63, w = t >> 6, q = l >> 4, nl = l & 15;
    const int qh = q >> 1, qb = 2 * (q & 1), fq = 4 * q;
    const int ge = t >> 2, part = t & 3;

    bf16x8 w1f[4][4];
#pragma unroll
    for (int kc = 0; kc < 4; ++kc)
#pragma unroll
        for (int T = 0; T < 4; ++T)
            w1f[kc][T] = *(const bf16x8*)(pn1l + (((kc * 4 + T) * 64 + l) << 3));
    bf16x8 w2f[2][4];
#pragma unroll
    for (int c = 0; c < 2; ++c)
#pragma unroll
        for (int T = 0; T < 4; ++T)
            w2f[c][T] = *(const bf16x8*)(pn2l + (((c * 4 + T) * 64 + l) << 3));
    if (t < 64) { sb1[t] = b1v[t]; sb2[t] = b2v[t]; sb1n[t] = b1n[t]; }

    const int NT = (Nn + 63) / 64;
    for (int bt = blockIdx.x; bt < NT; bt += gridDim.x) {
        const int base = bt * 64;
        const int n_g = base + ge;
        __syncthreads();
        {
            if (n_g < Nn) {
                const bf16* hr = hbuf + ((size_t)n_g << 6) + part * 16;
                *(bf16x8*)&inB[(((part * 2 + 0) * 64) + ge) << 3] = *(const bf16x8*)(hr);
                *(bf16x8*)&inB[(((part * 2 + 1) * 64) + ge) << 3] = *(const bf16x8*)(hr + 8);
                float* mr = m_agg + ((size_t)n_g << 6) + part * 16;
                float4 m0 = *(const float4*)(mr + 0);
                float4 m1 = *(const float4*)(mr + 4);
                float4 m2 = *(const float4*)(mr + 8);
                float4 m3 = *(const float4*)(mr + 12);
                float4 z4 = {0.f, 0.f, 0.f, 0.f};
                *(float4*)(mr + 0) = z4;
                *(float4*)(mr + 4) = z4;
                *(float4*)(mr + 8) = z4;
                *(float4*)(mr + 12) = z4;
                bf16x8 bm0 = {(bf16)m0.x, (bf16)m0.y, (bf16)m0.z, (bf16)m0.w,
                              (bf16)m1.x, (bf16)m1.y, (bf16)m1.z, (bf16)m1.w};
                bf16x8 bm1 = {(bf16)m2.x, (bf16)m2.y, (bf16)m2.z, (bf16)m2.w,
                              (bf16)m3.x, (bf16)m3.y, (bf16)m3.z, (bf16)m3.w};
                *(bf16x8*)&inB[(((8 + part * 2 + 0) * 64) + ge) << 3] = bm0;
                *(bf16x8*)&inB[(((8 + part * 2 + 1) * 64) + ge) << 3] = bm1;
            } else {
                bf16x8 zz = {(bf16)0.f, (bf16)0.f, (bf16)0.f, (bf16)0.f,
                             (bf16)0.f, (bf16)0.f, (bf16)0.f, (bf16)0.f};
                *(bf16x8*)&inB[(((part * 2 + 0) * 64) + ge) << 3] = zz;
                *(bf16x8*)&inB[(((part * 2 + 1) * 64) + ge) << 3] = zz;
                *(bf16x8*)&inB[(((8 + part * 2 + 0) * 64) + ge) << 3] = zz;
                *(bf16x8*)&inB[(((8 + part * 2 + 1) * 64) + ge) << 3] = zz;
            }
        }
        __syncthreads();

        f32x4 a1[4];
#pragma unroll
        for (int T = 0; T < 4; ++T) a1[T] = (f32x4){0.f, 0.f, 0.f, 0.f};
#pragma unroll
        for (int kc = 0; kc < 4; ++kc) {
            bf16x8 bfrag = *(const bf16x8*)&inB[(((kc * 4 + q) * 64) + w * 16 + nl) << 3];
#pragma unroll
            for (int T = 0; T < 4; ++T)
                a1[T] = __builtin_amdgcn_mfma_f32_16x16x32_bf16(w1f[kc][T], bfrag, a1[T], 0, 0, 0);
        }
        int pk[4][2];
#pragma unroll
        for (int T = 0; T < 4; ++T) {
            const float4 bq = *(const float4*)&sb1[T * 16 + fq];
            float h0 = silu_f(a1[T][0] + bq.x);
            float h1 = silu_f(a1[T][1] + bq.y);
            float h2 = silu_f(a1[T][2] + bq.z);
            float h3 = silu_f(a1[T][3] + bq.w);
            pk[T][0] = pack2bf(h0, h1);
            pk[T][1] = pack2bf(h2, h3);
        }
        f32x4 a2[4];
#pragma unroll
        for (int T = 0; T < 4; ++T) a2[T] = (f32x4){0.f, 0.f, 0.f, 0.f};
#pragma unroll
        for (int c = 0; c < 2; ++c) {
            union { int i[4]; bf16x8 v; } bu;
#pragma unroll
            for (int d = 0; d < 4; ++d) {
                int src = (qb + (d >> 1)) * 16 + nl;
                int t0 = __shfl(pk[2 * c][d & 1], src);
                int t1 = __shfl(pk[2 * c + 1][d & 1], src);
                bu.i[d] = qh ? t1 : t0;
            }
#pragma unroll
            for (int T = 0; T < 4; ++T)
                a2[T] = __builtin_amdgcn_mfma_f32_16x16x32_bf16(w2f[c][T], bu.v, a2[T], 0, 0, 0);
        }
#pragma unroll
        for (int T = 0; T < 4; ++T) {
            const float4 bq = *(const float4*)&sb2[T * 16 + fq];
            dhT[(T * 16 + fq + 0) * 65 + w * 16 + nl] = a2[T][0] + bq.x;
            dhT[(T * 16 + fq + 1) * 65 + w * 16 + nl] = a2[T][1] + bq.y;
            dhT[(T * 16 + fq + 2) * 65 + w * 16 + nl] = a2[T][2] + bq.z;
            dhT[(T * 16 + fq + 3) * 65 + w * 16 + nl] = a2[T][3] + bq.w;
        }
        __syncthreads();
        {
            if (n_g < Nn) {
                bf16x4 hv[4];
#pragma unroll
                for (int j = 0; j < 4; ++j) {
                    int f = part * 16 + j * 4;
                    float4* hp = (float4*)(h + ((size_t)n_g << 6) + f);
                    float4 old = *hp;
                    old.x += dhT[(f + 0) * 65 + ge];
                    old.y += dhT[(f + 1) * 65 + ge];
                    old.z += dhT[(f + 2) * 65 + ge];
                    old.w += dhT[(f + 3) * 65 + ge];
                    *hp = old;
                    hv[j] = (bf16x4){(bf16)old.x, (bf16)old.y, (bf16)old.z, (bf16)old.w};
                    *(bf16x4*)(hbuf + ((size_t)n_g << 6) + f) = hv[j];
                }
                if (donext) {
                    union { bf16x4 h2[2]; bf16x8 v; } u0, u1;
                    u0.h2[0] = hv[0]; u0.h2[1] = hv[1];
                    u1.h2[0] = hv[2]; u1.h2[1] = hv[3];
                    *(bf16x8*)&inB[(((part * 2 + 0) * 64) + ge) << 3] = u0.v;
                    *(bf16x8*)&inB[(((part * 2 + 1) * 64) + ge) << 3] = u1.v;
                }
            } else if (donext) {
                bf16x8 zz = {(bf16)0.f, (bf16)0.f, (bf16)0.f, (bf16)0.f,
                             (bf16)0.f, (bf16)0.f, (bf16)0.f, (bf16)0.f};
                *(bf16x8*)&inB[(((part * 2 + 0) * 64) + ge) << 3] = zz;
                *(bf16x8*)&inB[(((part * 2 + 1) * 64) + ge) << 3] = zz;
            }
        }
        if (t < 64) {
            int n = base + t;
            if (n < Nn) {
#pragma unroll
                for (int c = 0; c < 3; ++c) {
                    x[n * 3 + c] += x_acc[n * 3 + c];
                    x_acc[n * 3 + c] = 0.f;
                }
            }
        }
        if (!donext) continue;
        __syncthreads();
        f32x4 apa[4], apb[4];
#pragma unroll
        for (int T = 0; T < 4; ++T) {
            apa[T] = (f32x4){0.f, 0.f, 0.f, 0.f};
            apb[T] = (f32x4){0.f, 0.f, 0.f, 0.f};
        }
#pragma unroll
        for (int kc = 0; kc < 2; ++kc) {
            bf16x8 bfrag = *(const bf16x8*)&inB[(((kc * 4 + q) * 64) + w * 16 + nl) << 3];
#pragma unroll
            for (int T = 0; T < 4; ++T) {
                bf16x8 wa = *(const bf16x8*)(pw1n + (((kc * 4 + T) * 64 + l) << 3));
                bf16x8 wb = *(const bf16x8*)(pw1n + ((((kc + 2) * 4 + T) * 64 + l) << 3));
                apa[T] = __builtin_amdgcn_mfma_f32_16x16x32_bf16(wa, bfrag, apa[T], 0, 0, 0);
                apb[T] = __builtin_amdgcn_mfma_f32_16x16x32_bf16(wb, bfrag, apb[T], 0, 0, 0);
            }
        }
#pragma unroll
        for (int T = 0; T < 4; ++T) {
#pragma unroll
            for (int r = 0; r < 4; ++r)
                dhT[(T * 16 + fq + r) * 65 + w * 16 + nl] = apa[T][r] + sb1n[T * 16 + fq + r];
        }
        __syncthreads();
        if (n_g < Nn) {
#pragma unroll
            for (int j = 0; j < 4; ++j) {
                int f = part * 16 + j * 4;
                bf16x4 bv = {(bf16)dhT[(f + 0) * 65 + ge], (bf16)dhT[(f + 1) * 65 + ge],
                             (bf16)dhT[(f + 2) * 65 + ge], (bf16)dhT[(f + 3) * 65 + ge]};
                *(bf16x4*)(Pa + ((size_t)n_g << 6) + f) = bv;
            }
        }
        __syncthreads();
#pragma unroll
        for (int T = 0; T < 4; ++T) {
#pragma unroll
            for (int r = 0; r < 4; ++r)
                dhT[(T * 16 + fq + r) * 65 + w * 16 + nl] = apb[T][r];
        }
        __syncthreads();
        if (n_g < Nn) {
#pragma unroll
            for (int j = 0; j < 4; ++j) {
                int f = part * 16 + j * 4;
                bf16x4 bv = {(bf16)dhT[(f + 0) * 65 + ge], (bf16)dhT[(f + 1) * 65 + ge],
                             (bf16)dhT[(f + 2) * 65 + ge], (bf16)dhT[(f + 3) * 65 + ge]};
                *(bf16x4*)(Pb + ((size_t)n_g << 6) + f) = bv;
            }
        }
    }
}

// ---------------- readout q (MFMA) + batch stats fused ----------------
__global__ __launch_bounds__(256) void k_q(
    const bf16* __restrict__ hbuf, const bf16* __restrict__ pq1,
    const float* __restrict__ b1v, const float* __restrict__ w2v,
    const float* __restrict__ b2v, float* __restrict__ qout,
    const int* __restrict__ batch, const float* __restrict__ x,
    float* __restrict__ cnt, float* __restrict__ xs) {
    __shared__ __align__(16) bf16 inB[8 * 64 * 8];
    __shared__ __align__(16) float sb1[64], sw2[64];
    const int t = threadIdx.x;
    const int l = t & 63, w = t >> 6, q = l >> 4, nl = l & 15;
    const int fq = 4 * q;
    const int ge = t >> 2, part = t & 3;

    bf16x8 w1f[2][4];
#pragma unroll
    for (int kc = 0; kc < 2; ++kc)
#pragma unroll
        for (int T = 0; T < 4; ++T)
            w1f[kc][T] = *(const bf16x8*)(pq1 + (((kc * 4 + T) * 64 + l) << 3));
    if (t < 64) { sb1[t] = b1v[t]; sw2[t] = w2v[t]; }
    const float qb2 = b2v[0];

    const int base = blockIdx.x * 64;
    if (t < 64) {
        int n = base + t;
        if (n < Nn) {
            int b = batch[n];
            atomicAdd(&cnt[b], 1.f);
            atomicAdd(&xs[b * 3 + 0], x[n * 3 + 0]);
            atomicAdd(&xs[b * 3 + 1], x[n * 3 + 1]);
            atomicAdd(&xs[b * 3 + 2], x[n * 3 + 2]);
        }
    }
    {
        int n = base + ge;
        if (n < Nn) {
            const bf16* hr = hbuf + ((size_t)n << 6) + part * 16;
            *(bf16x8*)&inB[(((part * 2 + 0) * 64) + ge) << 3] = *(const bf16x8*)(hr);
            *(bf16x8*)&inB[(((part * 2 + 1) * 64) + ge) << 3] = *(const bf16x8*)(hr + 8);
        } else {
            bf16x8 zz = {(bf16)0.f, (bf16)0.f, (bf16)0.f, (bf16)0.f,
                         (bf16)0.f, (bf16)0.f, (bf16)0.f, (bf16)0.f};
            *(bf16x8*)&inB[(((part * 2 + 0) * 64) + ge) << 3] = zz;
            *(bf16x8*)&inB[(((part * 2 + 1) * 64) + ge) << 3] = zz;
        }
    }
    __syncthreads();
    f32x4 a1[4];
#pragma unroll
    for (int T = 0; T < 4; ++T) a1[T] = (f32x4){0.f, 0.f, 0.f, 0.f};
#pragma unroll
    for (int kc = 0; kc < 2; ++kc) {
        bf16x8 bfrag = *(const bf16x8*)&inB[(((kc * 4 + q) * 64) + w * 16 + nl) << 3];
#pragma unroll
        for (int T = 0; T < 4; ++T)
            a1[T] = __builtin_amdgcn_mfma_f32_16x16x32_bf16(w1f[kc][T], bfrag, a1[T], 0, 0, 0);
    }
    float pc = 0.f;
#pragma unroll
    for (int T = 0; T < 4; ++T) {
        const float4 bq = *(const float4*)&sb1[T * 16 + fq];
        const float4 cq = *(const float4*)&sw2[T * 16 + fq];
        pc += silu_f(a1[T][0] + bq.x) * cq.x;
        pc += silu_f(a1[T][1] + bq.y) * cq.y;
        pc += silu_f(a1[T][2] + bq.z) * cq.z;
        pc += silu_f(a1[T][3] + bq.w) * cq.w;
    }
    pc += __shfl_xor(pc, 16);
    pc += __shfl_xor(pc, 32);
    if (q == 0) {
        int n = base + w * 16 + nl;
        if (n < Nn) qout[n] = pc + qb2;
    }
}

__global__ void k_mu(const int* __restrict__ batch, const float* __restrict__ x,
                     const float* __restrict__ q, const float* __restrict__ cnt,
                     const float* __restrict__ xs, float* __restrict__ out) {
    int n = blockIdx.x * blockDim.x + threadIdx.x;
    if (n < Nn) {
        int b = batch[n];
        float cc = fmaxf(cnt[b], 1.f);
        float qn = q[n];
#pragma unroll
        for (int c = 0; c < 3; ++c) {
            float xr = x[n * 3 + c] - xs[b * 3 + c] / cc;
            atomicAdd(&out[b * 3 + c], qn * xr);
        }
    }
}

// ---------------- launch ----------------
extern "C" void kernel_launch(void* const* d_in, const int* in_sizes, int n_in,
                              void* d_out, int out_size, void* d_ws, size_t ws_size,
                              hipStream_t stream) {
    const int* z = (const int*)d_in[0];
    const float* pos = (const float*)d_in[1];
    const int* ei0 = (const int*)d_in[2];
    const int* ei1 = ei0 + Ee;
    const int* batch = (const int*)d_in[3];
    const float* emb = (const float*)d_in[4];
    const float* eW1 = (const float*)d_in[5];
    const float* eb1 = (const float*)d_in[6];
    const float* eW2 = (const float*)d_in[7];
    const float* eb2 = (const float*)d_in[8];
    const float* cW = (const float*)d_in[9];
    const float* cb = (const float*)d_in[10];
    const float* nW1 = (const float*)d_in[11];
    const float* nb1 = (const float*)d_in[12];
    const float* nW2 = (const float*)d_in[13];
    const float* nb2 = (const float*)d_in[14];
    const float* qW1 = (const float*)d_in[15];
    const float* qb1 = (const float*)d_in[16];
    const float* qW2 = (const float*)d_in[17];
    const float* qb2 = (const float*)d_in[18];

    char* ws = (char*)d_ws;
    size_t o = 0;
    auto alloc = [&](size_t bytes) {
        size_t r = o;
        o = (o + bytes + 255) & ~(size_t)255;
        return r;
    };
    float* h = (float*)(ws + alloc((size_t)Nn * 64 * 4));
    float* xp = (float*)(ws + alloc((size_t)Nn * 3 * 4));
    float* magg = (float*)(ws + alloc((size_t)Nn * 64 * 4));
    float* xacc = (float*)(ws + alloc((size_t)Nn * 3 * 4));
    size_t zero_span = (size_t)((char*)xacc - (char*)magg) + (size_t)Nn * 3 * 4;
    float* qv = (float*)(ws + alloc((size_t)Nn * 4));
    int* deg = (int*)(ws + alloc((size_t)Nn * 4));
    int* cur = (int*)(ws + alloc((size_t)Nn * 4));
    int* rows_s = (int*)(ws + alloc((size_t)Ee * 4));
    int* cols_s = (int*)(ws + alloc((size_t)Ee * 4));
    float* cnt = (float*)(ws + alloc((size_t)Bb * 4));
    float* xs = (float*)(ws + alloc((size_t)Bb * 3 * 4));
    bf16* hbm = (bf16*)(ws + alloc((size_t)Nn * 64 * 2));
    bf16* Pa = (bf16*)(ws + alloc((size_t)Nn * 64 * 2));
    bf16* Pb = (bf16*)(ws + alloc((size_t)Nn * 64 * 2));
    bf16* pw1 = (bf16*)(ws + alloc((size_t)4 * 8192 * 2));
    bf16* pw2 = (bf16*)(ws + alloc((size_t)4 * 4096 * 2));
    bf16* pn1 = (bf16*)(ws + alloc((size_t)4 * 8192 * 2));
    bf16* pn2 = (bf16*)(ws + alloc((size_t)4 * 4096 * 2));
    bf16* pq1 = (bf16*)(ws + alloc((size_t)4096 * 2));
    int* bsum = (int*)(ws + alloc((size_t)NB * 4));
    int* boff = (int*)(ws + alloc((size_t)NB * 4));

    hipMemsetAsync(deg, 0, (size_t)Nn * 4, stream);
    hipMemsetAsync(magg, 0, zero_span, stream);
    hipMemsetAsync(cnt, 0, (size_t)Bb * 4, stream);
    hipMemsetAsync(xs, 0, (size_t)Bb * 3 * 4, stream);
    hipMemsetAsync(d_out, 0, (size_t)out_size * 4, stream);

    hipMemcpyAsync(xp, pos, (size_t)Nn * 3 * 4, hipMemcpyDeviceToDevice, stream);
    k_setup<<<2048, 256, 0, stream>>>(h, hbm, z, emb, eW1, eW2, nW1, nW2, qW1,
                                      pw1, pw2, pn1, pn2, pq1, ei0, deg);
    k_scan1<<<NB, 256, 0, stream>>>(deg, bsum);
    k_scan2<<<1, 256, 0, stream>>>(bsum, boff);
    k_scan3<<<NB, 256, 0, stream>>>(deg, boff, cur, rows_s);
    k_scatter<<<(Ee + 255) / 256, 256, 0, stream>>>(ei0, ei1, cur, cols_s);

    k_proj<<<782, 256, 0, stream>>>(hbm, pw1, eb1, Pa, Pb);
    for (int l = 0; l < 4; ++l) {
        k_edge<<<6250, 256, 0, stream>>>(rows_s, cols_s, Pa, Pb, xp,
                                         pw2 + (size_t)l * 4096,
                                         eW1 + (size_t)l * 129 * 64,
                                         eb2 + l * 64,
                                         cW + l * 64, cb + l, magg, xacc);
        int nx = (l < 3) ? (l + 1) : 0;
        k_node<<<782, 256, 0, stream>>>(magg, xacc,
                                        pn1 + (size_t)l * 8192, pn2 + (size_t)l * 4096,
                                        nb1 + l * 64, nb2 + l * 64,
                                        h, hbm, xp,
                                        pw1 + (size_t)nx * 8192, eb1 + nx * 64,
                                        Pa, Pb, (l < 3) ? 1 : 0);
    }
    k_q<<<(Nn + 63) / 64, 256, 0, stream>>>(hbm, pq1, qb1, qW2, qb2, qv,
                                            batch, xp, cnt, xs);
    k_mu<<<(Nn + 255) / 256, 256, 0, stream>>>(batch, xp, qv, cnt, xs, (float*)d_out);
}

// Round 17
// 974.246 us; speedup vs baseline: 1.3711x; 1.3711x over previous
//
#include <hip/hip_runtime.h>
#include <math.h>

#define Nn 50000
#define Ee 1600000
#define Bb 512
#define TE 64
#define NTILES (Ee / TE)
#define NB ((Nn + 255) / 256)

typedef __bf16 bf16;
typedef __bf16 bf16x8 __attribute__((ext_vector_type(8)));
typedef __bf16 bf16x4 __attribute__((ext_vector_type(4)));
typedef float f32x4 __attribute__((ext_vector_type(4)));

__device__ __forceinline__ float silu_f(float v) {
    return v * __builtin_amdgcn_rcpf(1.f + __expf(-v));
}
__device__ __forceinline__ float tanh_f(float x) {
    float e = __expf(2.f * x);
    return 1.f - 2.f * __builtin_amdgcn_rcpf(e + 1.f);
}
__device__ __forceinline__ int pack2bf(float a, float b) {
    unsigned short ua = __builtin_bit_cast(unsigned short, (bf16)a);
    unsigned short ub = __builtin_bit_cast(unsigned short, (bf16)b);
    return (int)ua | ((int)ub << 16);
}
__device__ __forceinline__ float unlo(int v) {
    return __builtin_bit_cast(float, v << 16);
}
__device__ __forceinline__ float unhi(int v) {
    return __builtin_bit_cast(float, v & 0xffff0000);
}

// ---------------- weight packing into MFMA A-fragment order ----------------
__device__ __forceinline__ void packfrag(bf16* dst, const float* src, int idx) {
    int j = idx & 7, lane = (idx >> 3) & 63, gT = idx >> 9;
    int kc = gT >> 2, T = gT & 3;
    int k = kc * 32 + (lane >> 4) * 8 + j;
    int n = T * 16 + (lane & 15);
    dst[idx] = (bf16)src[k * 64 + n];
}

// fused setup: h=emb[z] (fp32+bf16), weight packing, degree histogram (independent jobs)
#define SETUP_TOT (Nn * 64 + 102400 + Ee)
__global__ void k_setup(float* __restrict__ h, bf16* __restrict__ hb,
                        const int* __restrict__ z, const float* __restrict__ emb,
                        const float* __restrict__ eW1, const float* __restrict__ eW2,
                        const float* __restrict__ nW1, const float* __restrict__ nW2,
                        const float* __restrict__ qW1,
                        bf16* __restrict__ pw1, bf16* __restrict__ pw2,
                        bf16* __restrict__ pn1, bf16* __restrict__ pn2,
                        bf16* __restrict__ pq1,
                        const int* __restrict__ rows, int* __restrict__ deg) {
    for (int i = blockIdx.x * blockDim.x + threadIdx.x; i < SETUP_TOT;
         i += gridDim.x * blockDim.x) {
        if (i < Nn * 64) {
            int n = i >> 6, f = i & 63;
            float v = emb[z[n] * 64 + f];
            h[i] = v;
            hb[i] = (bf16)v;
        } else if (i < Nn * 64 + 102400) {
            int tid = i - Nn * 64;
            if (tid < 32768) {
                int l = tid >> 13, idx = tid & 8191;
                packfrag(pw1 + l * 8192, eW1 + (size_t)l * 129 * 64, idx);
            } else if (tid < 49152) {
                int k = tid - 32768, l = k >> 12, idx = k & 4095;
                packfrag(pw2 + l * 4096, eW2 + (size_t)l * 4096, idx);
            } else if (tid < 81920) {
                int k = tid - 49152, l = k >> 13, idx = k & 8191;
                packfrag(pn1 + l * 8192, nW1 + (size_t)l * 8192, idx);
            } else if (tid < 98304) {
                int k = tid - 81920, l = k >> 12, idx = k & 4095;
                packfrag(pn2 + l * 4096, nW2 + (size_t)l * 4096, idx);
            } else {
                packfrag(pq1, qW1, tid - 98304);
            }
        } else {
            int e = i - Nn * 64 - 102400;
            atomicAdd(&deg[rows[e]], 1);
        }
    }
}

__global__ void k_scan1(const int* __restrict__ deg, int* __restrict__ bsum) {
    __shared__ int red[4];
    int b = blockIdx.x;
    int i = b * 256 + threadIdx.x;
    int v = (i < Nn) ? deg[i] : 0;
#pragma unroll
    for (int off = 1; off < 64; off <<= 1) v += __shfl_xor(v, off);
    if ((threadIdx.x & 63) == 0) red[threadIdx.x >> 6] = v;
    __syncthreads();
    if (threadIdx.x == 0) bsum[b] = red[0] + red[1] + red[2] + red[3];
}

__global__ void k_scan2(const int* __restrict__ bsum, int* __restrict__ boff) {
    __shared__ int s[256];
    int t = threadIdx.x;
    int v = (t < NB) ? bsum[t] : 0;
    s[t] = v;
    __syncthreads();
    for (int off = 1; off < 256; off <<= 1) {
        int u = (t >= off) ? s[t - off] : 0;
        __syncthreads();
        s[t] += u;
        __syncthreads();
    }
    if (t < NB) boff[t] = s[t] - v;
}

// fused: exclusive scan -> cur (scatter cursor) + rows_s expansion
__global__ void k_scan3(const int* __restrict__ deg, const int* __restrict__ boff,
                        int* __restrict__ cur, int* __restrict__ rows_s) {
    __shared__ int s[256];
    int b = blockIdx.x, t = threadIdx.x;
    int i = b * 256 + t;
    int v = (i < Nn) ? deg[i] : 0;
    s[t] = v;
    __syncthreads();
    for (int off = 1; off < 256; off <<= 1) {
        int u = (t >= off) ? s[t - off] : 0;
        __syncthreads();
        s[t] += u;
        __syncthreads();
    }
    if (i < Nn) {
        int en = boff[b] + s[t];
        int st = en - v;
        cur[i] = st;
        for (int o = st; o < en; ++o) rows_s[o] = i;
    }
}

// cols-only scatter; cur holds absolute offsets
__global__ void k_scatter(const int* __restrict__ rows, const int* __restrict__ cols,
                          int* __restrict__ cur, int* __restrict__ cols_s) {
    int e = blockIdx.x * blockDim.x + threadIdx.x;
    if (e < Ee) {
        int o = atomicAdd(&cur[rows[e]], 1);
        cols_s[o] = cols[e];
    }
}

// ---------------- layer-0 node projection: Pa = H@W1a + b1, Pb = H@W1b (bf16 out) ----------------
__global__ __launch_bounds__(256) void k_proj(
    const bf16* __restrict__ hbuf, const bf16* __restrict__ pw1l,
    const float* __restrict__ b1v,
    bf16* __restrict__ Pa, bf16* __restrict__ Pb) {
    __shared__ __align__(16) bf16 inB[8 * 64 * 8];
    __shared__ float dhT[64 * 65];
    __shared__ __align__(16) float sb1[64];

    const int t = threadIdx.x;
    const int l = t & 63, w = t >> 6, q = l >> 4, nl = l & 15;
    const int fq = 4 * q;
    const int ge = t >> 2, part = t & 3;

    bf16x8 w1f[4][4];
#pragma unroll
    for (int kc = 0; kc < 4; ++kc)
#pragma unroll
        for (int T = 0; T < 4; ++T)
            w1f[kc][T] = *(const bf16x8*)(pw1l + (((kc * 4 + T) * 64 + l) << 3));
    if (t < 64) sb1[t] = b1v[t];

    const int NT = (Nn + 63) / 64;
    for (int bt = blockIdx.x; bt < NT; bt += gridDim.x) {
        const int base = bt * 64;
        __syncthreads();
        {
            int n = base + ge;
            if (n < Nn) {
                const bf16* hr = hbuf + ((size_t)n << 6) + part * 16;
                *(bf16x8*)&inB[(((part * 2 + 0) * 64) + ge) << 3] = *(const bf16x8*)(hr);
                *(bf16x8*)&inB[(((part * 2 + 1) * 64) + ge) << 3] = *(const bf16x8*)(hr + 8);
            } else {
                bf16x8 zz = {(bf16)0.f, (bf16)0.f, (bf16)0.f, (bf16)0.f,
                             (bf16)0.f, (bf16)0.f, (bf16)0.f, (bf16)0.f};
                *(bf16x8*)&inB[(((part * 2 + 0) * 64) + ge) << 3] = zz;
                *(bf16x8*)&inB[(((part * 2 + 1) * 64) + ge) << 3] = zz;
            }
        }
        __syncthreads();

        f32x4 apa[4], apb[4];
#pragma unroll
        for (int T = 0; T < 4; ++T) {
            apa[T] = (f32x4){0.f, 0.f, 0.f, 0.f};
            apb[T] = (f32x4){0.f, 0.f, 0.f, 0.f};
        }
#pragma unroll
        for (int kc = 0; kc < 2; ++kc) {
            bf16x8 bfrag = *(const bf16x8*)&inB[(((kc * 4 + q) * 64) + w * 16 + nl) << 3];
#pragma unroll
            for (int T = 0; T < 4; ++T) {
                apa[T] = __builtin_amdgcn_mfma_f32_16x16x32_bf16(w1f[kc][T], bfrag, apa[T], 0, 0, 0);
                apb[T] = __builtin_amdgcn_mfma_f32_16x16x32_bf16(w1f[kc + 2][T], bfrag, apb[T], 0, 0, 0);
            }
        }
#pragma unroll
        for (int T = 0; T < 4; ++T) {
#pragma unroll
            for (int r = 0; r < 4; ++r)
                dhT[(T * 16 + fq + r) * 65 + w * 16 + nl] = apa[T][r] + sb1[T * 16 + fq + r];
        }
        __syncthreads();
        {
            int n = base + ge;
            if (n < Nn) {
#pragma unroll
                for (int j = 0; j < 4; ++j) {
                    int f = part * 16 + j * 4;
                    bf16x4 bv = {(bf16)dhT[(f + 0) * 65 + ge], (bf16)dhT[(f + 1) * 65 + ge],
                                 (bf16)dhT[(f + 2) * 65 + ge], (bf16)dhT[(f + 3) * 65 + ge]};
                    *(bf16x4*)(Pa + ((size_t)n << 6) + f) = bv;
                }
            }
        }
        __syncthreads();
#pragma unroll
        for (int T = 0; T < 4; ++T) {
#pragma unroll
            for (int r = 0; r < 4; ++r)
                dhT[(T * 16 + fq + r) * 65 + w * 16 + nl] = apb[T][r];
        }
        __syncthreads();
        {
            int n = base + ge;
            if (n < Nn) {
#pragma unroll
                for (int j = 0; j < 4; ++j) {
                    int f = part * 16 + j * 4;
                    bf16x4 bv = {(bf16)dhT[(f + 0) * 65 + ge], (bf16)dhT[(f + 1) * 65 + ge],
                                 (bf16)dhT[(f + 2) * 65 + ge], (bf16)dhT[(f + 3) * 65 + ge]};
                    *(bf16x4*)(Pb + ((size_t)n << 6) + f) = bv;
                }
            }
        }
    }
}

// ---------------- edge kernel: gather bf16 Pa/Pb, fragment-native layout (no shuffle repack) ----------------
// Thread (w, q, nl) owns edge eo+nl and B-fragment k-slots {c2*32 + q*8 + j}.
// B-frag mapping (verified vs old shuffle net): k = 32*c2 + 8*q + j, col n = nl.
// MEASURED-BEST STATE (974.8 us total, k_edge 138 us). Two refuted variants:
//  - R4 XCD swizzle + 4 consecutive tiles/block: FETCH 139->158MB, dur +2% (worse L2)
//  - R8 register gather pipeline: scratch spill under 64-VGPR cap, FETCH 4x, dur +57%
__global__ __launch_bounds__(256, 8) void k_edge(
    const int* __restrict__ rows_s, const int* __restrict__ cols_s,
    const bf16* __restrict__ Pa, const bf16* __restrict__ Pb,
    const float* __restrict__ x,
    const bf16* __restrict__ pw2l,
    const float* __restrict__ w1f32,
    const float* __restrict__ b2v,
    const float* __restrict__ cwv, const float* __restrict__ cbv,
    float* __restrict__ m_agg, float* __restrict__ x_acc) {
    __shared__ __align__(16) bf16 lw2[4096];
    __shared__ __align__(16) float w128s[64], b2s[64], cws[64];
    __shared__ int mEp[32 * 65];
    __shared__ __align__(16) float relsm[64 * 4];
    __shared__ float coefs[64];
    __shared__ int srow[64];

    const int t = threadIdx.x;
    const int l = t & 63, w = t >> 6, q = l >> 4, nl = l & 15;
    const int fq = 4 * q;

    {
        const int4* s2 = (const int4*)pw2l;
        int4* d2p = (int4*)lw2;
#pragma unroll
        for (int i = 0; i < 2; ++i) d2p[t + 256 * i] = s2[t + 256 * i];
        if (t < 64) {
            w128s[t] = w1f32[128 * 64 + t];
            b2s[t] = b2v[t];
            cws[t] = cwv[t];
        }
    }
    const float cb0 = cbv[0];
    __syncthreads();

    // tile-invariant dist2-weight quads for this thread's k-slots (hoisted)
    const float4 w00 = *(const float4*)&w128s[q * 8 + 0];
    const float4 w01 = *(const float4*)&w128s[q * 8 + 4];
    const float4 w10 = *(const float4*)&w128s[32 + q * 8 + 0];
    const float4 w11 = *(const float4*)&w128s[32 + q * 8 + 4];

    for (int tile = blockIdx.x; tile < NTILES; tile += gridDim.x) {
        const int eo = tile * TE + w * 16;
        const int eg = eo + nl;

        const int r_g = rows_s[eg], c_g = cols_s[eg];
        float rx = x[r_g * 3 + 0] - x[c_g * 3 + 0];
        float ry = x[r_g * 3 + 1] - x[c_g * 3 + 1];
        float rz = x[r_g * 3 + 2] - x[c_g * 3 + 2];
        float d2 = fmaf(rx, rx, fmaf(ry, ry, rz * rz));
        if (q == 0) {
            srow[w * 16 + nl] = r_g;
            float4 rv;
            rv.x = rx; rv.y = ry; rv.z = rz; rv.w = d2;
            *(float4*)&relsm[(w * 16 + nl) * 4] = rv;
        }

        const bf16* par = Pa + ((size_t)r_g << 6) + q * 8;
        const bf16* pbc = Pb + ((size_t)c_g << 6) + q * 8;
        int4 A0 = *(const int4*)(par);
        int4 A1 = *(const int4*)(par + 32);
        int4 B0 = *(const int4*)(pbc);
        int4 B1 = *(const int4*)(pbc + 32);

        union { int i[4]; bf16x8 v; } bu0, bu1;
        bu0.i[0] = pack2bf(silu_f(fmaf(w00.x, d2, unlo(A0.x) + unlo(B0.x))),
                           silu_f(fmaf(w00.y, d2, unhi(A0.x) + unhi(B0.x))));
        bu0.i[1] = pack2bf(silu_f(fmaf(w00.z, d2, unlo(A0.y) + unlo(B0.y))),
                           silu_f(fmaf(w00.w, d2, unhi(A0.y) + unhi(B0.y))));
        bu0.i[2] = pack2bf(silu_f(fmaf(w01.x, d2, unlo(A0.z) + unlo(B0.z))),
                           silu_f(fmaf(w01.y, d2, unhi(A0.z) + unhi(B0.z))));
        bu0.i[3] = pack2bf(silu_f(fmaf(w01.z, d2, unlo(A0.w) + unlo(B0.w))),
                           silu_f(fmaf(w01.w, d2, unhi(A0.w) + unhi(B0.w))));
        bu1.i[0] = pack2bf(silu_f(fmaf(w10.x, d2, unlo(A1.x) + unlo(B1.x))),
                           silu_f(fmaf(w10.y, d2, unhi(A1.x) + unhi(B1.x))));
        bu1.i[1] = pack2bf(silu_f(fmaf(w10.z, d2, unlo(A1.y) + unlo(B1.y))),
                           silu_f(fmaf(w10.w, d2, unhi(A1.y) + unhi(B1.y))));
        bu1.i[2] = pack2bf(silu_f(fmaf(w11.x, d2, unlo(A1.z) + unlo(B1.z))),
                           silu_f(fmaf(w11.y, d2, unhi(A1.z) + unhi(B1.z))));
        bu1.i[3] = pack2bf(silu_f(fmaf(w11.z, d2, unlo(A1.w) + unlo(B1.w))),
                           silu_f(fmaf(w11.w, d2, unhi(A1.w) + unhi(B1.w))));

        f32x4 a2[4];
#pragma unroll
        for (int T = 0; T < 4; ++T) a2[T] = (f32x4){0.f, 0.f, 0.f, 0.f};
#pragma unroll
        for (int T = 0; T < 4; ++T) {
            bf16x8 wf = *(const bf16x8*)&lw2[(((0 * 4 + T) * 64) + l) << 3];
            a2[T] = __builtin_amdgcn_mfma_f32_16x16x32_bf16(wf, bu0.v, a2[T], 0, 0, 0);
        }
#pragma unroll
        for (int T = 0; T < 4; ++T) {
            bf16x8 wf = *(const bf16x8*)&lw2[(((1 * 4 + T) * 64) + l) << 3];
            a2[T] = __builtin_amdgcn_mfma_f32_16x16x32_bf16(wf, bu1.v, a2[T], 0, 0, 0);
        }
        float pc = 0.f;
#pragma unroll
        for (int T = 0; T < 4; ++T) {
            const float4 bq = *(const float4*)&b2s[T * 16 + fq];
            const float4 cq = *(const float4*)&cws[T * 16 + fq];
            float m0 = silu_f(a2[T][0] + bq.x);
            float m1 = silu_f(a2[T][1] + bq.y);
            float m2 = silu_f(a2[T][2] + bq.z);
            float m3 = silu_f(a2[T][3] + bq.w);
            int p0 = (T * 16 + fq) >> 1;
            mEp[(p0 + 0) * 65 + w * 16 + nl] = pack2bf(m0, m1);
            mEp[(p0 + 1) * 65 + w * 16 + nl] = pack2bf(m2, m3);
            pc += m0 * cq.x + m1 * cq.y + m2 * cq.z + m3 * cq.w;
        }
        pc += __shfl_xor(pc, 16);
        pc += __shfl_xor(pc, 32);
        if (q == 0) coefs[w * 16 + nl] = tanh_f(pc + cb0);
        __syncthreads();  // barrier A

        {
            int rl = srow[l];
            int rprev = __shfl(rl, l - 1);
            bool isst = (l == 0) || (rl != rprev);
            unsigned long long mask = __ballot(isst);
            const int pair = l & 31, half = l >> 5;
            unsigned long long mm = mask;
            int s = 0;
            while (mm) {
                int st = __ffsll(mm) - 1;
                mm &= mm - 1;
                if ((s & 3) == w) {
                    int en = mm ? (__ffsll(mm) - 1) : TE;
                    int row = __shfl(rl, st);
                    float s0 = 0.f, s1 = 0.f, sx = 0.f;
                    for (int e = st + half; e < en; e += 2) {
                        int pv = mEp[pair * 65 + e];
                        s0 += __builtin_bit_cast(float, pv << 16);
                        s1 += __builtin_bit_cast(float, pv & 0xffff0000);
                    }
                    if (half == 1 && pair < 3) {
                        for (int e = st; e < en; ++e)
                            sx += relsm[e * 4 + pair] * coefs[e];
                    }
                    s0 += __shfl_xor(s0, 32);
                    s1 += __shfl_xor(s1, 32);
                    if (half == 0) {
                        atomicAdd(m_agg + (size_t)row * 64 + 2 * pair, s0);
                        atomicAdd(m_agg + (size_t)row * 64 + 2 * pair + 1, s1);
                    } else if (pair < 3) {
                        atomicAdd(x_acc + (size_t)row * 3 + pair, sx);
                    }
                }
                s++;
            }
        }
        __syncthreads();  // barrier B
    }
}

// ---------------- node kernel (MFMA, grid-stride; fused next-layer projection; zeroes accumulators) ----------------
__global__ __launch_bounds__(256) void k_node(
    float* __restrict__ m_agg, float* __restrict__ x_acc,
    const bf16* __restrict__ pn1l, const bf16* __restrict__ pn2l,
    const float* __restrict__ b1v, const float* __restrict__ b2v,
    float* __restrict__ h, bf16* __restrict__ hbuf, float* __restrict__ x,
    const bf16* __restrict__ pw1n, const float* __restrict__ b1n,
    bf16* __restrict__ Pa, bf16* __restrict__ Pb, int donext) {
    __shared__ __align__(16) bf16 inB[16 * 64 * 8];
    __shared__ float dhT[64 * 65];
    __shared__ __align__(16) float sb1[64], sb2[64], sb1n[64];

    const int t = threadIdx.x;
    const int l = t & 63, w = t >> 6, q = l >> 4, nl = l & 15;
    const int qh = q >> 1, qb = 2 * (q & 1), fq = 4 * q;
    const int ge = t >> 2, part = t & 3;

    bf16x8 w1f[4][4];
#pragma unroll
    for (int kc = 0; kc < 4; ++kc)
#pragma unroll
        for (int T = 0; T < 4; ++T)
            w1f[kc][T] = *(const bf16x8*)(pn1l + (((kc * 4 + T) * 64 + l) << 3));
    bf16x8 w2f[2][4];
#pragma unroll
    for (int c = 0; c < 2; ++c)
#pragma unroll
        for (int T = 0; T < 4; ++T)
            w2f[c][T] = *(const bf16x8*)(pn2l + (((c * 4 + T) * 64 + l) << 3));
    if (t < 64) { sb1[t] = b1v[t]; sb2[t] = b2v[t]; sb1n[t] = b1n[t]; }

    const int NT = (Nn + 63) / 64;
    for (int bt = blockIdx.x; bt < NT; bt += gridDim.x) {
        const int base = bt * 64;
        const int n_g = base + ge;
        __syncthreads();
        {
            if (n_g < Nn) {
                const bf16* hr = hbuf + ((size_t)n_g << 6) + part * 16;
                *(bf16x8*)&inB[(((part * 2 + 0) * 64) + ge) << 3] = *(const bf16x8*)(hr);
                *(bf16x8*)&inB[(((part * 2 + 1) * 64) + ge) << 3] = *(const bf16x8*)(hr + 8);
                float* mr = m_agg + ((size_t)n_g << 6) + part * 16;
                float4 m0 = *(const float4*)(mr + 0);
                float4 m1 = *(const float4*)(mr + 4);
                float4 m2 = *(const float4*)(mr + 8);
                float4 m3 = *(const float4*)(mr + 12);
                float4 z4 = {0.f, 0.f, 0.f, 0.f};
                *(float4*)(mr + 0) = z4;
                *(float4*)(mr + 4) = z4;
                *(float4*)(mr + 8) = z4;
                *(float4*)(mr + 12) = z4;
                bf16x8 bm0 = {(bf16)m0.x, (bf16)m0.y, (bf16)m0.z, (bf16)m0.w,
                              (bf16)m1.x, (bf16)m1.y, (bf16)m1.z, (bf16)m1.w};
                bf16x8 bm1 = {(bf16)m2.x, (bf16)m2.y, (bf16)m2.z, (bf16)m2.w,
                              (bf16)m3.x, (bf16)m3.y, (bf16)m3.z, (bf16)m3.w};
                *(bf16x8*)&inB[(((8 + part * 2 + 0) * 64) + ge) << 3] = bm0;
                *(bf16x8*)&inB[(((8 + part * 2 + 1) * 64) + ge) << 3] = bm1;
            } else {
                bf16x8 zz = {(bf16)0.f, (bf16)0.f, (bf16)0.f, (bf16)0.f,
                             (bf16)0.f, (bf16)0.f, (bf16)0.f, (bf16)0.f};
                *(bf16x8*)&inB[(((part * 2 + 0) * 64) + ge) << 3] = zz;
                *(bf16x8*)&inB[(((part * 2 + 1) * 64) + ge) << 3] = zz;
                *(bf16x8*)&inB[(((8 + part * 2 + 0) * 64) + ge) << 3] = zz;
                *(bf16x8*)&inB[(((8 + part * 2 + 1) * 64) + ge) << 3] = zz;
            }
        }
        __syncthreads();

        f32x4 a1[4];
#pragma unroll
        for (int T = 0; T < 4; ++T) a1[T] = (f32x4){0.f, 0.f, 0.f, 0.f};
#pragma unroll
        for (int kc = 0; kc < 4; ++kc) {
            bf16x8 bfrag = *(const bf16x8*)&inB[(((kc * 4 + q) * 64) + w * 16 + nl) << 3];
#pragma unroll
            for (int T = 0; T < 4; ++T)
                a1[T] = __builtin_amdgcn_mfma_f32_16x16x32_bf16(w1f[kc][T], bfrag, a1[T], 0, 0, 0);
        }
        int pk[4][2];
#pragma unroll
        for (int T = 0; T < 4; ++T) {
            const float4 bq = *(const float4*)&sb1[T * 16 + fq];
            float h0 = silu_f(a1[T][0] + bq.x);
            float h1 = silu_f(a1[T][1] + bq.y);
            float h2 = silu_f(a1[T][2] + bq.z);
            float h3 = silu_f(a1[T][3] + bq.w);
            pk[T][0] = pack2bf(h0, h1);
            pk[T][1] = pack2bf(h2, h3);
        }
        f32x4 a2[4];
#pragma unroll
        for (int T = 0; T < 4; ++T) a2[T] = (f32x4){0.f, 0.f, 0.f, 0.f};
#pragma unroll
        for (int c = 0; c < 2; ++c) {
            union { int i[4]; bf16x8 v; } bu;
#pragma unroll
            for (int d = 0; d < 4; ++d) {
                int src = (qb + (d >> 1)) * 16 + nl;
                int t0 = __shfl(pk[2 * c][d & 1], src);
                int t1 = __shfl(pk[2 * c + 1][d & 1], src);
                bu.i[d] = qh ? t1 : t0;
            }
#pragma unroll
            for (int T = 0; T < 4; ++T)
                a2[T] = __builtin_amdgcn_mfma_f32_16x16x32_bf16(w2f[c][T], bu.v, a2[T], 0, 0, 0);
        }
#pragma unroll
        for (int T = 0; T < 4; ++T) {
            const float4 bq = *(const float4*)&sb2[T * 16 + fq];
            dhT[(T * 16 + fq + 0) * 65 + w * 16 + nl] = a2[T][0] + bq.x;
            dhT[(T * 16 + fq + 1) * 65 + w * 16 + nl] = a2[T][1] + bq.y;
            dhT[(T * 16 + fq + 2) * 65 + w * 16 + nl] = a2[T][2] + bq.z;
            dhT[(T * 16 + fq + 3) * 65 + w * 16 + nl] = a2[T][3] + bq.w;
        }
        __syncthreads();
        {
            if (n_g < Nn) {
                bf16x4 hv[4];
#pragma unroll
                for (int j = 0; j < 4; ++j) {
                    int f = part * 16 + j * 4;
                    float4* hp = (float4*)(h + ((size_t)n_g << 6) + f);
                    float4 old = *hp;
                    old.x += dhT[(f + 0) * 65 + ge];
                    old.y += dhT[(f + 1) * 65 + ge];
                    old.z += dhT[(f + 2) * 65 + ge];
                    old.w += dhT[(f + 3) * 65 + ge];
                    *hp = old;
                    hv[j] = (bf16x4){(bf16)old.x, (bf16)old.y, (bf16)old.z, (bf16)old.w};
                    *(bf16x4*)(hbuf + ((size_t)n_g << 6) + f) = hv[j];
                }
                if (donext) {
                    union { bf16x4 h2[2]; bf16x8 v; } u0, u1;
                    u0.h2[0] = hv[0]; u0.h2[1] = hv[1];
                    u1.h2[0] = hv[2]; u1.h2[1] = hv[3];
                    *(bf16x8*)&inB[(((part * 2 + 0) * 64) + ge) << 3] = u0.v;
                    *(bf16x8*)&inB[(((part * 2 + 1) * 64) + ge) << 3] = u1.v;
                }
            } else if (donext) {
                bf16x8 zz = {(bf16)0.f, (bf16)0.f, (bf16)0.f, (bf16)0.f,
                             (bf16)0.f, (bf16)0.f, (bf16)0.f, (bf16)0.f};
                *(bf16x8*)&inB[(((part * 2 + 0) * 64) + ge) << 3] = zz;
                *(bf16x8*)&inB[(((part * 2 + 1) * 64) + ge) << 3] = zz;
            }
        }
        if (t < 64) {
            int n = base + t;
            if (n < Nn) {
#pragma unroll
                for (int c = 0; c < 3; ++c) {
                    x[n * 3 + c] += x_acc[n * 3 + c];
                    x_acc[n * 3 + c] = 0.f;
                }
            }
        }
        if (!donext) continue;
        __syncthreads();
        f32x4 apa[4], apb[4];
#pragma unroll
        for (int T = 0; T < 4; ++T) {
            apa[T] = (f32x4){0.f, 0.f, 0.f, 0.f};
            apb[T] = (f32x4){0.f, 0.f, 0.f, 0.f};
        }
#pragma unroll
        for (int kc = 0; kc < 2; ++kc) {
            bf16x8 bfrag = *(const bf16x8*)&inB[(((kc * 4 + q) * 64) + w * 16 + nl) << 3];
#pragma unroll
            for (int T = 0; T < 4; ++T) {
                bf16x8 wa = *(const bf16x8*)(pw1n + (((kc * 4 + T) * 64 + l) << 3));
                bf16x8 wb = *(const bf16x8*)(pw1n + ((((kc + 2) * 4 + T) * 64 + l) << 3));
                apa[T] = __builtin_amdgcn_mfma_f32_16x16x32_bf16(wa, bfrag, apa[T], 0, 0, 0);
                apb[T] = __builtin_amdgcn_mfma_f32_16x16x32_bf16(wb, bfrag, apb[T], 0, 0, 0);
            }
        }
#pragma unroll
        for (int T = 0; T < 4; ++T) {
#pragma unroll
            for (int r = 0; r < 4; ++r)
                dhT[(T * 16 + fq + r) * 65 + w * 16 + nl] = apa[T][r] + sb1n[T * 16 + fq + r];
        }
        __syncthreads();
        if (n_g < Nn) {
#pragma unroll
            for (int j = 0; j < 4; ++j) {
                int f = part * 16 + j * 4;
                bf16x4 bv = {(bf16)dhT[(f + 0) * 65 + ge], (bf16)dhT[(f + 1) * 65 + ge],
                             (bf16)dhT[(f + 2) * 65 + ge], (bf16)dhT[(f + 3) * 65 + ge]};
                *(bf16x4*)(Pa + ((size_t)n_g << 6) + f) = bv;
            }
        }
        __syncthreads();
#pragma unroll
        for (int T = 0; T < 4; ++T) {
#pragma unroll
            for (int r = 0; r < 4; ++r)
                dhT[(T * 16 + fq + r) * 65 + w * 16 + nl] = apb[T][r];
        }
        __syncthreads();
        if (n_g < Nn) {
#pragma unroll
            for (int j = 0; j < 4; ++j) {
                int f = part * 16 + j * 4;
                bf16x4 bv = {(bf16)dhT[(f + 0) * 65 + ge], (bf16)dhT[(f + 1) * 65 + ge],
                             (bf16)dhT[(f + 2) * 65 + ge], (bf16)dhT[(f + 3) * 65 + ge]};
                *(bf16x4*)(Pb + ((size_t)n_g << 6) + f) = bv;
            }
        }
    }
}

// ---------------- readout q (MFMA) + batch stats fused ----------------
__global__ __launch_bounds__(256) void k_q(
    const bf16* __restrict__ hbuf, const bf16* __restrict__ pq1,
    const float* __restrict__ b1v, const float* __restrict__ w2v,
    const float* __restrict__ b2v, float* __restrict__ qout,
    const int* __restrict__ batch, const float* __restrict__ x,
    float* __restrict__ cnt, float* __restrict__ xs) {
    __shared__ __align__(16) bf16 inB[8 * 64 * 8];
    __shared__ __align__(16) float sb1[64], sw2[64];
    const int t = threadIdx.x;
    const int l = t & 63, w = t >> 6, q = l >> 4, nl = l & 15;
    const int fq = 4 * q;
    const int ge = t >> 2, part = t & 3;

    bf16x8 w1f[2][4];
#pragma unroll
    for (int kc = 0; kc < 2; ++kc)
#pragma unroll
        for (int T = 0; T < 4; ++T)
            w1f[kc][T] = *(const bf16x8*)(pq1 + (((kc * 4 + T) * 64 + l) << 3));
    if (t < 64) { sb1[t] = b1v[t]; sw2[t] = w2v[t]; }
    const float qb2 = b2v[0];

    const int base = blockIdx.x * 64;
    if (t < 64) {
        int n = base + t;
        if (n < Nn) {
            int b = batch[n];
            atomicAdd(&cnt[b], 1.f);
            atomicAdd(&xs[b * 3 + 0], x[n * 3 + 0]);
            atomicAdd(&xs[b * 3 + 1], x[n * 3 + 1]);
            atomicAdd(&xs[b * 3 + 2], x[n * 3 + 2]);
        }
    }
    {
        int n = base + ge;
        if (n < Nn) {
            const bf16* hr = hbuf + ((size_t)n << 6) + part * 16;
            *(bf16x8*)&inB[(((part * 2 + 0) * 64) + ge) << 3] = *(const bf16x8*)(hr);
            *(bf16x8*)&inB[(((part * 2 + 1) * 64) + ge) << 3] = *(const bf16x8*)(hr + 8);
        } else {
            bf16x8 zz = {(bf16)0.f, (bf16)0.f, (bf16)0.f, (bf16)0.f,
                         (bf16)0.f, (bf16)0.f, (bf16)0.f, (bf16)0.f};
            *(bf16x8*)&inB[(((part * 2 + 0) * 64) + ge) << 3] = zz;
            *(bf16x8*)&inB[(((part * 2 + 1) * 64) + ge) << 3] = zz;
        }
    }
    __syncthreads();
    f32x4 a1[4];
#pragma unroll
    for (int T = 0; T < 4; ++T) a1[T] = (f32x4){0.f, 0.f, 0.f, 0.f};
#pragma unroll
    for (int kc = 0; kc < 2; ++kc) {
        bf16x8 bfrag = *(const bf16x8*)&inB[(((kc * 4 + q) * 64) + w * 16 + nl) << 3];
#pragma unroll
        for (int T = 0; T < 4; ++T)
            a1[T] = __builtin_amdgcn_mfma_f32_16x16x32_bf16(w1f[kc][T], bfrag, a1[T], 0, 0, 0);
    }
    float pc = 0.f;
#pragma unroll
    for (int T = 0; T < 4; ++T) {
        const float4 bq = *(const float4*)&sb1[T * 16 + fq];
        const float4 cq = *(const float4*)&sw2[T * 16 + fq];
        pc += silu_f(a1[T][0] + bq.x) * cq.x;
        pc += silu_f(a1[T][1] + bq.y) * cq.y;
        pc += silu_f(a1[T][2] + bq.z) * cq.z;
        pc += silu_f(a1[T][3] + bq.w) * cq.w;
    }
    pc += __shfl_xor(pc, 16);
    pc += __shfl_xor(pc, 32);
    if (q == 0) {
        int n = base + w * 16 + nl;
        if (n < Nn) qout[n] = pc + qb2;
    }
}

__global__ void k_mu(const int* __restrict__ batch, const float* __restrict__ x,
                     const float* __restrict__ q, const float* __restrict__ cnt,
                     const float* __restrict__ xs, float* __restrict__ out) {
    int n = blockIdx.x * blockDim.x + threadIdx.x;
    if (n < Nn) {
        int b = batch[n];
        float cc = fmaxf(cnt[b], 1.f);
        float qn = q[n];
#pragma unroll
        for (int c = 0; c < 3; ++c) {
            float xr = x[n * 3 + c] - xs[b * 3 + c] / cc;
            atomicAdd(&out[b * 3 + c], qn * xr);
        }
    }
}

// ---------------- launch ----------------
extern "C" void kernel_launch(void* const* d_in, const int* in_sizes, int n_in,
                              void* d_out, int out_size, void* d_ws, size_t ws_size,
                              hipStream_t stream) {
    const int* z = (const int*)d_in[0];
    const float* pos = (const float*)d_in[1];
    const int* ei0 = (const int*)d_in[2];
    const int* ei1 = ei0 + Ee;
    const int* batch = (const int*)d_in[3];
    const float* emb = (const float*)d_in[4];
    const float* eW1 = (const float*)d_in[5];
    const float* eb1 = (const float*)d_in[6];
    const float* eW2 = (const float*)d_in[7];
    const float* eb2 = (const float*)d_in[8];
    const float* cW = (const float*)d_in[9];
    const float* cb = (const float*)d_in[10];
    const float* nW1 = (const float*)d_in[11];
    const float* nb1 = (const float*)d_in[12];
    const float* nW2 = (const float*)d_in[13];
    const float* nb2 = (const float*)d_in[14];
    const float* qW1 = (const float*)d_in[15];
    const float* qb1 = (const float*)d_in[16];
    const float* qW2 = (const float*)d_in[17];
    const float* qb2 = (const float*)d_in[18];

    char* ws = (char*)d_ws;
    size_t o = 0;
    auto alloc = [&](size_t bytes) {
        size_t r = o;
        o = (o + bytes + 255) & ~(size_t)255;
        return r;
    };
    float* h = (float*)(ws + alloc((size_t)Nn * 64 * 4));
    float* xp = (float*)(ws + alloc((size_t)Nn * 3 * 4));
    float* magg = (float*)(ws + alloc((size_t)Nn * 64 * 4));
    float* xacc = (float*)(ws + alloc((size_t)Nn * 3 * 4));
    size_t zero_span = (size_t)((char*)xacc - (char*)magg) + (size_t)Nn * 3 * 4;
    float* qv = (float*)(ws + alloc((size_t)Nn * 4));
    int* deg = (int*)(ws + alloc((size_t)Nn * 4));
    int* cur = (int*)(ws + alloc((size_t)Nn * 4));
    int* rows_s = (int*)(ws + alloc((size_t)Ee * 4));
    int* cols_s = (int*)(ws + alloc((size_t)Ee * 4));
    float* cnt = (float*)(ws + alloc((size_t)Bb * 4));
    float* xs = (float*)(ws + alloc((size_t)Bb * 3 * 4));
    bf16* hbm = (bf16*)(ws + alloc((size_t)Nn * 64 * 2));
    bf16* Pa = (bf16*)(ws + alloc((size_t)Nn * 64 * 2));
    bf16* Pb = (bf16*)(ws + alloc((size_t)Nn * 64 * 2));
    bf16* pw1 = (bf16*)(ws + alloc((size_t)4 * 8192 * 2));
    bf16* pw2 = (bf16*)(ws + alloc((size_t)4 * 4096 * 2));
    bf16* pn1 = (bf16*)(ws + alloc((size_t)4 * 8192 * 2));
    bf16* pn2 = (bf16*)(ws + alloc((size_t)4 * 4096 * 2));
    bf16* pq1 = (bf16*)(ws + alloc((size_t)4096 * 2));
    int* bsum = (int*)(ws + alloc((size_t)NB * 4));
    int* boff = (int*)(ws + alloc((size_t)NB * 4));

    hipMemsetAsync(deg, 0, (size_t)Nn * 4, stream);
    hipMemsetAsync(magg, 0, zero_span, stream);
    hipMemsetAsync(cnt, 0, (size_t)Bb * 4, stream);
    hipMemsetAsync(xs, 0, (size_t)Bb * 3 * 4, stream);
    hipMemsetAsync(d_out, 0, (size_t)out_size * 4, stream);

    hipMemcpyAsync(xp, pos, (size_t)Nn * 3 * 4, hipMemcpyDeviceToDevice, stream);
    k_setup<<<2048, 256, 0, stream>>>(h, hbm, z, emb, eW1, eW2, nW1, nW2, qW1,
                                      pw1, pw2, pn1, pn2, pq1, ei0, deg);
    k_scan1<<<NB, 256, 0, stream>>>(deg, bsum);
    k_scan2<<<1, 256, 0, stream>>>(bsum, boff);
    k_scan3<<<NB, 256, 0, stream>>>(deg, boff, cur, rows_s);
    k_scatter<<<(Ee + 255) / 256, 256, 0, stream>>>(ei0, ei1, cur, cols_s);

    k_proj<<<782, 256, 0, stream>>>(hbm, pw1, eb1, Pa, Pb);
    for (int l = 0; l < 4; ++l) {
        k_edge<<<6250, 256, 0, stream>>>(rows_s, cols_s, Pa, Pb, xp,
                                         pw2 + (size_t)l * 4096,
                                         eW1 + (size_t)l * 129 * 64,
                                         eb2 + l * 64,
                                         cW + l * 64, cb + l, magg, xacc);
        int nx = (l < 3) ? (l + 1) : 0;
        k_node<<<782, 256, 0, stream>>>(magg, xacc,
                                        pn1 + (size_t)l * 8192, pn2 + (size_t)l * 4096,
                                        nb1 + l * 64, nb2 + l * 64,
                                        h, hbm, xp,
                                        pw1 + (size_t)nx * 8192, eb1 + nx * 64,
                                        Pa, Pb, (l < 3) ? 1 : 0);
    }
    k_q<<<(Nn + 63) / 64, 256, 0, stream>>>(hbm, pq1, qb1, qW2, qb2, qv,
                                            batch, xp, cnt, xs);
    k_mu<<<(Nn + 255) / 256, 256, 0, stream>>>(batch, xp, qv, cnt, xs, (float*)d_out);
}

// Round 21
// 972.967 us; speedup vs baseline: 1.3729x; 1.0013x over previous
//
#include <hip/hip_runtime.h>
#include <math.h>

#define Nn 50000
#define Ee 1600000
#define Bb 512
#define TE 64
#define NTILES (Ee / TE)
#define NB ((Nn + 255) / 256)

typedef __bf16 bf16;
typedef __bf16 bf16x8 __attribute__((ext_vector_type(8)));
typedef __bf16 bf16x4 __attribute__((ext_vector_type(4)));
typedef float f32x4 __attribute__((ext_vector_type(4)));

__device__ __forceinline__ float silu_f(float v) {
    return v * __builtin_amdgcn_rcpf(1.f + __expf(-v));
}
__device__ __forceinline__ float tanh_f(float x) {
    float e = __expf(2.f * x);
    return 1.f - 2.f * __builtin_amdgcn_rcpf(e + 1.f);
}
__device__ __forceinline__ int pack2bf(float a, float b) {
    unsigned short ua = __builtin_bit_cast(unsigned short, (bf16)a);
    unsigned short ub = __builtin_bit_cast(unsigned short, (bf16)b);
    return (int)ua | ((int)ub << 16);
}
__device__ __forceinline__ float unlo(int v) {
    return __builtin_bit_cast(float, v << 16);
}
__device__ __forceinline__ float unhi(int v) {
    return __builtin_bit_cast(float, v & 0xffff0000);
}

// ---------------- weight packing into MFMA A-fragment order ----------------
__device__ __forceinline__ void packfrag(bf16* dst, const float* src, int idx) {
    int j = idx & 7, lane = (idx >> 3) & 63, gT = idx >> 9;
    int kc = gT >> 2, T = gT & 3;
    int k = kc * 32 + (lane >> 4) * 8 + j;
    int n = T * 16 + (lane & 15);
    dst[idx] = (bf16)src[k * 64 + n];
}

// fused setup: h=emb[z] (fp32+bf16), weight packing, degree histogram (independent jobs)
#define SETUP_TOT (Nn * 64 + 102400 + Ee)
__global__ void k_setup(float* __restrict__ h, bf16* __restrict__ hb,
                        const int* __restrict__ z, const float* __restrict__ emb,
                        const float* __restrict__ eW1, const float* __restrict__ eW2,
                        const float* __restrict__ nW1, const float* __restrict__ nW2,
                        const float* __restrict__ qW1,
                        bf16* __restrict__ pw1, bf16* __restrict__ pw2,
                        bf16* __restrict__ pn1, bf16* __restrict__ pn2,
                        bf16* __restrict__ pq1,
                        const int* __restrict__ rows, int* __restrict__ deg) {
    for (int i = blockIdx.x * blockDim.x + threadIdx.x; i < SETUP_TOT;
         i += gridDim.x * blockDim.x) {
        if (i < Nn * 64) {
            int n = i >> 6, f = i & 63;
            float v = emb[z[n] * 64 + f];
            h[i] = v;
            hb[i] = (bf16)v;
        } else if (i < Nn * 64 + 102400) {
            int tid = i - Nn * 64;
            if (tid < 32768) {
                int l = tid >> 13, idx = tid & 8191;
                packfrag(pw1 + l * 8192, eW1 + (size_t)l * 129 * 64, idx);
            } else if (tid < 49152) {
                int k = tid - 32768, l = k >> 12, idx = k & 4095;
                packfrag(pw2 + l * 4096, eW2 + (size_t)l * 4096, idx);
            } else if (tid < 81920) {
                int k = tid - 49152, l = k >> 13, idx = k & 8191;
                packfrag(pn1 + l * 8192, nW1 + (size_t)l * 8192, idx);
            } else if (tid < 98304) {
                int k = tid - 81920, l = k >> 12, idx = k & 4095;
                packfrag(pn2 + l * 4096, nW2 + (size_t)l * 4096, idx);
            } else {
                packfrag(pq1, qW1, tid - 98304);
            }
        } else {
            int e = i - Nn * 64 - 102400;
            atomicAdd(&deg[rows[e]], 1);
        }
    }
}

__global__ void k_scan1(const int* __restrict__ deg, int* __restrict__ bsum) {
    __shared__ int red[4];
    int b = blockIdx.x;
    int i = b * 256 + threadIdx.x;
    int v = (i < Nn) ? deg[i] : 0;
#pragma unroll
    for (int off = 1; off < 64; off <<= 1) v += __shfl_xor(v, off);
    if ((threadIdx.x & 63) == 0) red[threadIdx.x >> 6] = v;
    __syncthreads();
    if (threadIdx.x == 0) bsum[b] = red[0] + red[1] + red[2] + red[3];
}

__global__ void k_scan2(const int* __restrict__ bsum, int* __restrict__ boff) {
    __shared__ int s[256];
    int t = threadIdx.x;
    int v = (t < NB) ? bsum[t] : 0;
    s[t] = v;
    __syncthreads();
    for (int off = 1; off < 256; off <<= 1) {
        int u = (t >= off) ? s[t - off] : 0;
        __syncthreads();
        s[t] += u;
        __syncthreads();
    }
    if (t < NB) boff[t] = s[t] - v;
}

// fused: exclusive scan -> cur (scatter cursor) + rows_s expansion
__global__ void k_scan3(const int* __restrict__ deg, const int* __restrict__ boff,
                        int* __restrict__ cur, int* __restrict__ rows_s) {
    __shared__ int s[256];
    int b = blockIdx.x, t = threadIdx.x;
    int i = b * 256 + t;
    int v = (i < Nn) ? deg[i] : 0;
    s[t] = v;
    __syncthreads();
    for (int off = 1; off < 256; off <<= 1) {
        int u = (t >= off) ? s[t - off] : 0;
        __syncthreads();
        s[t] += u;
        __syncthreads();
    }
    if (i < Nn) {
        int en = boff[b] + s[t];
        int st = en - v;
        cur[i] = st;
        for (int o = st; o < en; ++o) rows_s[o] = i;
    }
}

// cols-only scatter; cur holds absolute offsets
__global__ void k_scatter(const int* __restrict__ rows, const int* __restrict__ cols,
                          int* __restrict__ cur, int* __restrict__ cols_s) {
    int e = blockIdx.x * blockDim.x + threadIdx.x;
    if (e < Ee) {
        int o = atomicAdd(&cur[rows[e]], 1);
        cols_s[o] = cols[e];
    }
}

// ---------------- layer-0 node projection: Pa = H@W1a + b1, Pb = H@W1b (bf16 out) ----------------
__global__ __launch_bounds__(256) void k_proj(
    const bf16* __restrict__ hbuf, const bf16* __restrict__ pw1l,
    const float* __restrict__ b1v,
    bf16* __restrict__ Pa, bf16* __restrict__ Pb) {
    __shared__ __align__(16) bf16 inB[8 * 64 * 8];
    __shared__ float dhT[64 * 65];
    __shared__ __align__(16) float sb1[64];

    const int t = threadIdx.x;
    const int l = t & 63, w = t >> 6, q = l >> 4, nl = l & 15;
    const int fq = 4 * q;
    const int ge = t >> 2, part = t & 3;

    bf16x8 w1f[4][4];
#pragma unroll
    for (int kc = 0; kc < 4; ++kc)
#pragma unroll
        for (int T = 0; T < 4; ++T)
            w1f[kc][T] = *(const bf16x8*)(pw1l + (((kc * 4 + T) * 64 + l) << 3));
    if (t < 64) sb1[t] = b1v[t];

    const int NT = (Nn + 63) / 64;
    for (int bt = blockIdx.x; bt < NT; bt += gridDim.x) {
        const int base = bt * 64;
        __syncthreads();
        {
            int n = base + ge;
            if (n < Nn) {
                const bf16* hr = hbuf + ((size_t)n << 6) + part * 16;
                *(bf16x8*)&inB[(((part * 2 + 0) * 64) + ge) << 3] = *(const bf16x8*)(hr);
                *(bf16x8*)&inB[(((part * 2 + 1) * 64) + ge) << 3] = *(const bf16x8*)(hr + 8);
            } else {
                bf16x8 zz = {(bf16)0.f, (bf16)0.f, (bf16)0.f, (bf16)0.f,
                             (bf16)0.f, (bf16)0.f, (bf16)0.f, (bf16)0.f};
                *(bf16x8*)&inB[(((part * 2 + 0) * 64) + ge) << 3] = zz;
                *(bf16x8*)&inB[(((part * 2 + 1) * 64) + ge) << 3] = zz;
            }
        }
        __syncthreads();

        f32x4 apa[4], apb[4];
#pragma unroll
        for (int T = 0; T < 4; ++T) {
            apa[T] = (f32x4){0.f, 0.f, 0.f, 0.f};
            apb[T] = (f32x4){0.f, 0.f, 0.f, 0.f};
        }
#pragma unroll
        for (int kc = 0; kc < 2; ++kc) {
            bf16x8 bfrag = *(const bf16x8*)&inB[(((kc * 4 + q) * 64) + w * 16 + nl) << 3];
#pragma unroll
            for (int T = 0; T < 4; ++T) {
                apa[T] = __builtin_amdgcn_mfma_f32_16x16x32_bf16(w1f[kc][T], bfrag, apa[T], 0, 0, 0);
                apb[T] = __builtin_amdgcn_mfma_f32_16x16x32_bf16(w1f[kc + 2][T], bfrag, apb[T], 0, 0, 0);
            }
        }
#pragma unroll
        for (int T = 0; T < 4; ++T) {
#pragma unroll
            for (int r = 0; r < 4; ++r)
                dhT[(T * 16 + fq + r) * 65 + w * 16 + nl] = apa[T][r] + sb1[T * 16 + fq + r];
        }
        __syncthreads();
        {
            int n = base + ge;
            if (n < Nn) {
#pragma unroll
                for (int j = 0; j < 4; ++j) {
                    int f = part * 16 + j * 4;
                    bf16x4 bv = {(bf16)dhT[(f + 0) * 65 + ge], (bf16)dhT[(f + 1) * 65 + ge],
                                 (bf16)dhT[(f + 2) * 65 + ge], (bf16)dhT[(f + 3) * 65 + ge]};
                    *(bf16x4*)(Pa + ((size_t)n << 6) + f) = bv;
                }
            }
        }
        __syncthreads();
#pragma unroll
        for (int T = 0; T < 4; ++T) {
#pragma unroll
            for (int r = 0; r < 4; ++r)
                dhT[(T * 16 + fq + r) * 65 + w * 16 + nl] = apb[T][r];
        }
        __syncthreads();
        {
            int n = base + ge;
            if (n < Nn) {
#pragma unroll
                for (int j = 0; j < 4; ++j) {
                    int f = part * 16 + j * 4;
                    bf16x4 bv = {(bf16)dhT[(f + 0) * 65 + ge], (bf16)dhT[(f + 1) * 65 + ge],
                                 (bf16)dhT[(f + 2) * 65 + ge], (bf16)dhT[(f + 3) * 65 + ge]};
                    *(bf16x4*)(Pb + ((size_t)n << 6) + f) = bv;
                }
            }
        }
    }
}

// ---------------- edge kernel: gather bf16 Pa/Pb, fragment-native layout (no shuffle repack) ----------------
// Thread (w, q, nl) owns edge eo+nl and B-fragment k-slots {c2*32 + q*8 + j}.
// B-frag mapping (verified vs old shuffle net): k = 32*c2 + 8*q + j, col n = nl.
// MEASURED-BEST STATE (974.2 us total, k_edge 137 us; confirmed twice). Refuted variants:
//  - R4 XCD swizzle + 4 consecutive tiles/block: FETCH 139->158MB, dur +2% (worse L2)
//  - R8 register gather pipeline @(256,8): scratch spill, FETCH 4x, dur +57%
//  - (256,4) pipeline retry: designed but never executed (broker failures); future work.
__global__ __launch_bounds__(256, 8) void k_edge(
    const int* __restrict__ rows_s, const int* __restrict__ cols_s,
    const bf16* __restrict__ Pa, const bf16* __restrict__ Pb,
    const float* __restrict__ x,
    const bf16* __restrict__ pw2l,
    const float* __restrict__ w1f32,
    const float* __restrict__ b2v,
    const float* __restrict__ cwv, const float* __restrict__ cbv,
    float* __restrict__ m_agg, float* __restrict__ x_acc) {
    __shared__ __align__(16) bf16 lw2[4096];
    __shared__ __align__(16) float w128s[64], b2s[64], cws[64];
    __shared__ int mEp[32 * 65];
    __shared__ __align__(16) float relsm[64 * 4];
    __shared__ float coefs[64];
    __shared__ int srow[64];

    const int t = threadIdx.x;
    const int l = t & 63, w = t >> 6, q = l >> 4, nl = l & 15;
    const int fq = 4 * q;

    {
        const int4* s2 = (const int4*)pw2l;
        int4* d2p = (int4*)lw2;
#pragma unroll
        for (int i = 0; i < 2; ++i) d2p[t + 256 * i] = s2[t + 256 * i];
        if (t < 64) {
            w128s[t] = w1f32[128 * 64 + t];
            b2s[t] = b2v[t];
            cws[t] = cwv[t];
        }
    }
    const float cb0 = cbv[0];
    __syncthreads();

    // tile-invariant dist2-weight quads for this thread's k-slots (hoisted)
    const float4 w00 = *(const float4*)&w128s[q * 8 + 0];
    const float4 w01 = *(const float4*)&w128s[q * 8 + 4];
    const float4 w10 = *(const float4*)&w128s[32 + q * 8 + 0];
    const float4 w11 = *(const float4*)&w128s[32 + q * 8 + 4];

    for (int tile = blockIdx.x; tile < NTILES; tile += gridDim.x) {
        const int eo = tile * TE + w * 16;
        const int eg = eo + nl;

        const int r_g = rows_s[eg], c_g = cols_s[eg];
        float rx = x[r_g * 3 + 0] - x[c_g * 3 + 0];
        float ry = x[r_g * 3 + 1] - x[c_g * 3 + 1];
        float rz = x[r_g * 3 + 2] - x[c_g * 3 + 2];
        float d2 = fmaf(rx, rx, fmaf(ry, ry, rz * rz));
        if (q == 0) {
            srow[w * 16 + nl] = r_g;
            float4 rv;
            rv.x = rx; rv.y = ry; rv.z = rz; rv.w = d2;
            *(float4*)&relsm[(w * 16 + nl) * 4] = rv;
        }

        const bf16* par = Pa + ((size_t)r_g << 6) + q * 8;
        const bf16* pbc = Pb + ((size_t)c_g << 6) + q * 8;
        int4 A0 = *(const int4*)(par);
        int4 A1 = *(const int4*)(par + 32);
        int4 B0 = *(const int4*)(pbc);
        int4 B1 = *(const int4*)(pbc + 32);

        union { int i[4]; bf16x8 v; } bu0, bu1;
        bu0.i[0] = pack2bf(silu_f(fmaf(w00.x, d2, unlo(A0.x) + unlo(B0.x))),
                           silu_f(fmaf(w00.y, d2, unhi(A0.x) + unhi(B0.x))));
        bu0.i[1] = pack2bf(silu_f(fmaf(w00.z, d2, unlo(A0.y) + unlo(B0.y))),
                           silu_f(fmaf(w00.w, d2, unhi(A0.y) + unhi(B0.y))));
        bu0.i[2] = pack2bf(silu_f(fmaf(w01.x, d2, unlo(A0.z) + unlo(B0.z))),
                           silu_f(fmaf(w01.y, d2, unhi(A0.z) + unhi(B0.z))));
        bu0.i[3] = pack2bf(silu_f(fmaf(w01.z, d2, unlo(A0.w) + unlo(B0.w))),
                           silu_f(fmaf(w01.w, d2, unhi(A0.w) + unhi(B0.w))));
        bu1.i[0] = pack2bf(silu_f(fmaf(w10.x, d2, unlo(A1.x) + unlo(B1.x))),
                           silu_f(fmaf(w10.y, d2, unhi(A1.x) + unhi(B1.x))));
        bu1.i[1] = pack2bf(silu_f(fmaf(w10.z, d2, unlo(A1.y) + unlo(B1.y))),
                           silu_f(fmaf(w10.w, d2, unhi(A1.y) + unhi(B1.y))));
        bu1.i[2] = pack2bf(silu_f(fmaf(w11.x, d2, unlo(A1.z) + unlo(B1.z))),
                           silu_f(fmaf(w11.y, d2, unhi(A1.z) + unhi(B1.z))));
        bu1.i[3] = pack2bf(silu_f(fmaf(w11.z, d2, unlo(A1.w) + unlo(B1.w))),
                           silu_f(fmaf(w11.w, d2, unhi(A1.w) + unhi(B1.w))));

        f32x4 a2[4];
#pragma unroll
        for (int T = 0; T < 4; ++T) a2[T] = (f32x4){0.f, 0.f, 0.f, 0.f};
#pragma unroll
        for (int T = 0; T < 4; ++T) {
            bf16x8 wf = *(const bf16x8*)&lw2[(((0 * 4 + T) * 64) + l) << 3];
            a2[T] = __builtin_amdgcn_mfma_f32_16x16x32_bf16(wf, bu0.v, a2[T], 0, 0, 0);
        }
#pragma unroll
        for (int T = 0; T < 4; ++T) {
            bf16x8 wf = *(const bf16x8*)&lw2[(((1 * 4 + T) * 64) + l) << 3];
            a2[T] = __builtin_amdgcn_mfma_f32_16x16x32_bf16(wf, bu1.v, a2[T], 0, 0, 0);
        }
        float pc = 0.f;
#pragma unroll
        for (int T = 0; T < 4; ++T) {
            const float4 bq = *(const float4*)&b2s[T * 16 + fq];
            const float4 cq = *(const float4*)&cws[T * 16 + fq];
            float m0 = silu_f(a2[T][0] + bq.x);
            float m1 = silu_f(a2[T][1] + bq.y);
            float m2 = silu_f(a2[T][2] + bq.z);
            float m3 = silu_f(a2[T][3] + bq.w);
            int p0 = (T * 16 + fq) >> 1;
            mEp[(p0 + 0) * 65 + w * 16 + nl] = pack2bf(m0, m1);
            mEp[(p0 + 1) * 65 + w * 16 + nl] = pack2bf(m2, m3);
            pc += m0 * cq.x + m1 * cq.y + m2 * cq.z + m3 * cq.w;
        }
        pc += __shfl_xor(pc, 16);
        pc += __shfl_xor(pc, 32);
        if (q == 0) coefs[w * 16 + nl] = tanh_f(pc + cb0);
        __syncthreads();  // barrier A

        {
            int rl = srow[l];
            int rprev = __shfl(rl, l - 1);
            bool isst = (l == 0) || (rl != rprev);
            unsigned long long mask = __ballot(isst);
            const int pair = l & 31, half = l >> 5;
            unsigned long long mm = mask;
            int s = 0;
            while (mm) {
                int st = __ffsll(mm) - 1;
                mm &= mm - 1;
                if ((s & 3) == w) {
                    int en = mm ? (__ffsll(mm) - 1) : TE;
                    int row = __shfl(rl, st);
                    float s0 = 0.f, s1 = 0.f, sx = 0.f;
                    for (int e = st + half; e < en; e += 2) {
                        int pv = mEp[pair * 65 + e];
                        s0 += __builtin_bit_cast(float, pv << 16);
                        s1 += __builtin_bit_cast(float, pv & 0xffff0000);
                    }
                    if (half == 1 && pair < 3) {
                        for (int e = st; e < en; ++e)
                            sx += relsm[e * 4 + pair] * coefs[e];
                    }
                    s0 += __shfl_xor(s0, 32);
                    s1 += __shfl_xor(s1, 32);
                    if (half == 0) {
                        atomicAdd(m_agg + (size_t)row * 64 + 2 * pair, s0);
                        atomicAdd(m_agg + (size_t)row * 64 + 2 * pair + 1, s1);
                    } else if (pair < 3) {
                        atomicAdd(x_acc + (size_t)row * 3 + pair, sx);
                    }
                }
                s++;
            }
        }
        __syncthreads();  // barrier B
    }
}

// ---------------- node kernel (MFMA, grid-stride; fused next-layer projection; zeroes accumulators) ----------------
__global__ __launch_bounds__(256) void k_node(
    float* __restrict__ m_agg, float* __restrict__ x_acc,
    const bf16* __restrict__ pn1l, const bf16* __restrict__ pn2l,
    const float* __restrict__ b1v, const float* __restrict__ b2v,
    float* __restrict__ h, bf16* __restrict__ hbuf, float* __restrict__ x,
    const bf16* __restrict__ pw1n, const float* __restrict__ b1n,
    bf16* __restrict__ Pa, bf16* __restrict__ Pb, int donext) {
    __shared__ __align__(16) bf16 inB[16 * 64 * 8];
    __shared__ float dhT[64 * 65];
    __shared__ __align__(16) float sb1[64], sb2[64], sb1n[64];

    const int t = threadIdx.x;
    const int l = t & 63, w = t >> 6, q = l >> 4, nl = l & 15;
    const int qh = q >> 1, qb = 2 * (q & 1), fq = 4 * q;
    const int ge = t >> 2, part = t & 3;

    bf16x8 w1f[4][4];
#pragma unroll
    for (int kc = 0; kc < 4; ++kc)
#pragma unroll
        for (int T = 0; T < 4; ++T)
            w1f[kc][T] = *(const bf16x8*)(pn1l + (((kc * 4 + T) * 64 + l) << 3));
    bf16x8 w2f[2][4];
#pragma unroll
    for (int c = 0; c < 2; ++c)
#pragma unroll
        for (int T = 0; T < 4; ++T)
            w2f[c][T] = *(const bf16x8*)(pn2l + (((c * 4 + T) * 64 + l) << 3));
    if (t < 64) { sb1[t] = b1v[t]; sb2[t] = b2v[t]; sb1n[t] = b1n[t]; }

    const int NT = (Nn + 63) / 64;
    for (int bt = blockIdx.x; bt < NT; bt += gridDim.x) {
        const int base = bt * 64;
        const int n_g = base + ge;
        __syncthreads();
        {
            if (n_g < Nn) {
                const bf16* hr = hbuf + ((size_t)n_g << 6) + part * 16;
                *(bf16x8*)&inB[(((part * 2 + 0) * 64) + ge) << 3] = *(const bf16x8*)(hr);
                *(bf16x8*)&inB[(((part * 2 + 1) * 64) + ge) << 3] = *(const bf16x8*)(hr + 8);
                float* mr = m_agg + ((size_t)n_g << 6) + part * 16;
                float4 m0 = *(const float4*)(mr + 0);
                float4 m1 = *(const float4*)(mr + 4);
                float4 m2 = *(const float4*)(mr + 8);
                float4 m3 = *(const float4*)(mr + 12);
                float4 z4 = {0.f, 0.f, 0.f, 0.f};
                *(float4*)(mr + 0) = z4;
                *(float4*)(mr + 4) = z4;
                *(float4*)(mr + 8) = z4;
                *(float4*)(mr + 12) = z4;
                bf16x8 bm0 = {(bf16)m0.x, (bf16)m0.y, (bf16)m0.z, (bf16)m0.w,
                              (bf16)m1.x, (bf16)m1.y, (bf16)m1.z, (bf16)m1.w};
                bf16x8 bm1 = {(bf16)m2.x, (bf16)m2.y, (bf16)m2.z, (bf16)m2.w,
                              (bf16)m3.x, (bf16)m3.y, (bf16)m3.z, (bf16)m3.w};
                *(bf16x8*)&inB[(((8 + part * 2 + 0) * 64) + ge) << 3] = bm0;
                *(bf16x8*)&inB[(((8 + part * 2 + 1) * 64) + ge) << 3] = bm1;
            } else {
                bf16x8 zz = {(bf16)0.f, (bf16)0.f, (bf16)0.f, (bf16)0.f,
                             (bf16)0.f, (bf16)0.f, (bf16)0.f, (bf16)0.f};
                *(bf16x8*)&inB[(((part * 2 + 0) * 64) + ge) << 3] = zz;
                *(bf16x8*)&inB[(((part * 2 + 1) * 64) + ge) << 3] = zz;
                *(bf16x8*)&inB[(((8 + part * 2 + 0) * 64) + ge) << 3] = zz;
                *(bf16x8*)&inB[(((8 + part * 2 + 1) * 64) + ge) << 3] = zz;
            }
        }
        __syncthreads();

        f32x4 a1[4];
#pragma unroll
        for (int T = 0; T < 4; ++T) a1[T] = (f32x4){0.f, 0.f, 0.f, 0.f};
#pragma unroll
        for (int kc = 0; kc < 4; ++kc) {
            bf16x8 bfrag = *(const bf16x8*)&inB[(((kc * 4 + q) * 64) + w * 16 + nl) << 3];
#pragma unroll
            for (int T = 0; T < 4; ++T)
                a1[T] = __builtin_amdgcn_mfma_f32_16x16x32_bf16(w1f[kc][T], bfrag, a1[T], 0, 0, 0);
        }
        int pk[4][2];
#pragma unroll
        for (int T = 0; T < 4; ++T) {
            const float4 bq = *(const float4*)&sb1[T * 16 + fq];
            float h0 = silu_f(a1[T][0] + bq.x);
            float h1 = silu_f(a1[T][1] + bq.y);
            float h2 = silu_f(a1[T][2] + bq.z);
            float h3 = silu_f(a1[T][3] + bq.w);
            pk[T][0] = pack2bf(h0, h1);
            pk[T][1] = pack2bf(h2, h3);
        }
        f32x4 a2[4];
#pragma unroll
        for (int T = 0; T < 4; ++T) a2[T] = (f32x4){0.f, 0.f, 0.f, 0.f};
#pragma unroll
        for (int c = 0; c < 2; ++c) {
            union { int i[4]; bf16x8 v; } bu;
#pragma unroll
            for (int d = 0; d < 4; ++d) {
                int src = (qb + (d >> 1)) * 16 + nl;
                int t0 = __shfl(pk[2 * c][d & 1], src);
                int t1 = __shfl(pk[2 * c + 1][d & 1], src);
                bu.i[d] = qh ? t1 : t0;
            }
#pragma unroll
            for (int T = 0; T < 4; ++T)
                a2[T] = __builtin_amdgcn_mfma_f32_16x16x32_bf16(w2f[c][T], bu.v, a2[T], 0, 0, 0);
        }
#pragma unroll
        for (int T = 0; T < 4; ++T) {
            const float4 bq = *(const float4*)&sb2[T * 16 + fq];
            dhT[(T * 16 + fq + 0) * 65 + w * 16 + nl] = a2[T][0] + bq.x;
            dhT[(T * 16 + fq + 1) * 65 + w * 16 + nl] = a2[T][1] + bq.y;
            dhT[(T * 16 + fq + 2) * 65 + w * 16 + nl] = a2[T][2] + bq.z;
            dhT[(T * 16 + fq + 3) * 65 + w * 16 + nl] = a2[T][3] + bq.w;
        }
        __syncthreads();
        {
            if (n_g < Nn) {
                bf16x4 hv[4];
#pragma unroll
                for (int j = 0; j < 4; ++j) {
                    int f = part * 16 + j * 4;
                    float4* hp = (float4*)(h + ((size_t)n_g << 6) + f);
                    float4 old = *hp;
                    old.x += dhT[(f + 0) * 65 + ge];
                    old.y += dhT[(f + 1) * 65 + ge];
                    old.z += dhT[(f + 2) * 65 + ge];
                    old.w += dhT[(f + 3) * 65 + ge];
                    *hp = old;
                    hv[j] = (bf16x4){(bf16)old.x, (bf16)old.y, (bf16)old.z, (bf16)old.w};
                    *(bf16x4*)(hbuf + ((size_t)n_g << 6) + f) = hv[j];
                }
                if (donext) {
                    union { bf16x4 h2[2]; bf16x8 v; } u0, u1;
                    u0.h2[0] = hv[0]; u0.h2[1] = hv[1];
                    u1.h2[0] = hv[2]; u1.h2[1] = hv[3];
                    *(bf16x8*)&inB[(((part * 2 + 0) * 64) + ge) << 3] = u0.v;
                    *(bf16x8*)&inB[(((part * 2 + 1) * 64) + ge) << 3] = u1.v;
                }
            } else if (donext) {
                bf16x8 zz = {(bf16)0.f, (bf16)0.f, (bf16)0.f, (bf16)0.f,
                             (bf16)0.f, (bf16)0.f, (bf16)0.f, (bf16)0.f};
                *(bf16x8*)&inB[(((part * 2 + 0) * 64) + ge) << 3] = zz;
                *(bf16x8*)&inB[(((part * 2 + 1) * 64) + ge) << 3] = zz;
            }
        }
        if (t < 64) {
            int n = base + t;
            if (n < Nn) {
#pragma unroll
                for (int c = 0; c < 3; ++c) {
                    x[n * 3 + c] += x_acc[n * 3 + c];
                    x_acc[n * 3 + c] = 0.f;
                }
            }
        }
        if (!donext) continue;
        __syncthreads();
        f32x4 apa[4], apb[4];
#pragma unroll
        for (int T = 0; T < 4; ++T) {
            apa[T] = (f32x4){0.f, 0.f, 0.f, 0.f};
            apb[T] = (f32x4){0.f, 0.f, 0.f, 0.f};
        }
#pragma unroll
        for (int kc = 0; kc < 2; ++kc) {
            bf16x8 bfrag = *(const bf16x8*)&inB[(((kc * 4 + q) * 64) + w * 16 + nl) << 3];
#pragma unroll
            for (int T = 0; T < 4; ++T) {
                bf16x8 wa = *(const bf16x8*)(pw1n + (((kc * 4 + T) * 64 + l) << 3));
                bf16x8 wb = *(const bf16x8*)(pw1n + ((((kc + 2) * 4 + T) * 64 + l) << 3));
                apa[T] = __builtin_amdgcn_mfma_f32_16x16x32_bf16(wa, bfrag, apa[T], 0, 0, 0);
                apb[T] = __builtin_amdgcn_mfma_f32_16x16x32_bf16(wb, bfrag, apb[T], 0, 0, 0);
            }
        }
#pragma unroll
        for (int T = 0; T < 4; ++T) {
#pragma unroll
            for (int r = 0; r < 4; ++r)
                dhT[(T * 16 + fq + r) * 65 + w * 16 + nl] = apa[T][r] + sb1n[T * 16 + fq + r];
        }
        __syncthreads();
        if (n_g < Nn) {
#pragma unroll
            for (int j = 0; j < 4; ++j) {
                int f = part * 16 + j * 4;
                bf16x4 bv = {(bf16)dhT[(f + 0) * 65 + ge], (bf16)dhT[(f + 1) * 65 + ge],
                             (bf16)dhT[(f + 2) * 65 + ge], (bf16)dhT[(f + 3) * 65 + ge]};
                *(bf16x4*)(Pa + ((size_t)n_g << 6) + f) = bv;
            }
        }
        __syncthreads();
#pragma unroll
        for (int T = 0; T < 4; ++T) {
#pragma unroll
            for (int r = 0; r < 4; ++r)
                dhT[(T * 16 + fq + r) * 65 + w * 16 + nl] = apb[T][r];
        }
        __syncthreads();
        if (n_g < Nn) {
#pragma unroll
            for (int j = 0; j < 4; ++j) {
                int f = part * 16 + j * 4;
                bf16x4 bv = {(bf16)dhT[(f + 0) * 65 + ge], (bf16)dhT[(f + 1) * 65 + ge],
                             (bf16)dhT[(f + 2) * 65 + ge], (bf16)dhT[(f + 3) * 65 + ge]};
                *(bf16x4*)(Pb + ((size_t)n_g << 6) + f) = bv;
            }
        }
    }
}

// ---------------- readout q (MFMA) + batch stats fused ----------------
__global__ __launch_bounds__(256) void k_q(
    const bf16* __restrict__ hbuf, const bf16* __restrict__ pq1,
    const float* __restrict__ b1v, const float* __restrict__ w2v,
    const float* __restrict__ b2v, float* __restrict__ qout,
    const int* __restrict__ batch, const float* __restrict__ x,
    float* __restrict__ cnt, float* __restrict__ xs) {
    __shared__ __align__(16) bf16 inB[8 * 64 * 8];
    __shared__ __align__(16) float sb1[64], sw2[64];
    const int t = threadIdx.x;
    const int l = t & 63, w = t >> 6, q = l >> 4, nl = l & 15;
    const int fq = 4 * q;
    const int ge = t >> 2, part = t & 3;

    bf16x8 w1f[2][4];
#pragma unroll
    for (int kc = 0; kc < 2; ++kc)
#pragma unroll
        for (int T = 0; T < 4; ++T)
            w1f[kc][T] = *(const bf16x8*)(pq1 + (((kc * 4 + T) * 64 + l) << 3));
    if (t < 64) { sb1[t] = b1v[t]; sw2[t] = w2v[t]; }
    const float qb2 = b2v[0];

    const int base = blockIdx.x * 64;
    if (t < 64) {
        int n = base + t;
        if (n < Nn) {
            int b = batch[n];
            atomicAdd(&cnt[b], 1.f);
            atomicAdd(&xs[b * 3 + 0], x[n * 3 + 0]);
            atomicAdd(&xs[b * 3 + 1], x[n * 3 + 1]);
            atomicAdd(&xs[b * 3 + 2], x[n * 3 + 2]);
        }
    }
    {
        int n = base + ge;
        if (n < Nn) {
            const bf16* hr = hbuf + ((size_t)n << 6) + part * 16;
            *(bf16x8*)&inB[(((part * 2 + 0) * 64) + ge) << 3] = *(const bf16x8*)(hr);
            *(bf16x8*)&inB[(((part * 2 + 1) * 64) + ge) << 3] = *(const bf16x8*)(hr + 8);
        } else {
            bf16x8 zz = {(bf16)0.f, (bf16)0.f, (bf16)0.f, (bf16)0.f,
                         (bf16)0.f, (bf16)0.f, (bf16)0.f, (bf16)0.f};
            *(bf16x8*)&inB[(((part * 2 + 0) * 64) + ge) << 3] = zz;
            *(bf16x8*)&inB[(((part * 2 + 1) * 64) + ge) << 3] = zz;
        }
    }
    __syncthreads();
    f32x4 a1[4];
#pragma unroll
    for (int T = 0; T < 4; ++T) a1[T] = (f32x4){0.f, 0.f, 0.f, 0.f};
#pragma unroll
    for (int kc = 0; kc < 2; ++kc) {
        bf16x8 bfrag = *(const bf16x8*)&inB[(((kc * 4 + q) * 64) + w * 16 + nl) << 3];
#pragma unroll
        for (int T = 0; T < 4; ++T)
            a1[T] = __builtin_amdgcn_mfma_f32_16x16x32_bf16(w1f[kc][T], bfrag, a1[T], 0, 0, 0);
    }
    float pc = 0.f;
#pragma unroll
    for (int T = 0; T < 4; ++T) {
        const float4 bq = *(const float4*)&sb1[T * 16 + fq];
        const float4 cq = *(const float4*)&sw2[T * 16 + fq];
        pc += silu_f(a1[T][0] + bq.x) * cq.x;
        pc += silu_f(a1[T][1] + bq.y) * cq.y;
        pc += silu_f(a1[T][2] + bq.z) * cq.z;
        pc += silu_f(a1[T][3] + bq.w) * cq.w;
    }
    pc += __shfl_xor(pc, 16);
    pc += __shfl_xor(pc, 32);
    if (q == 0) {
        int n = base + w * 16 + nl;
        if (n < Nn) qout[n] = pc + qb2;
    }
}

__global__ void k_mu(const int* __restrict__ batch, const float* __restrict__ x,
                     const float* __restrict__ q, const float* __restrict__ cnt,
                     const float* __restrict__ xs, float* __restrict__ out) {
    int n = blockIdx.x * blockDim.x + threadIdx.x;
    if (n < Nn) {
        int b = batch[n];
        float cc = fmaxf(cnt[b], 1.f);
        float qn = q[n];
#pragma unroll
        for (int c = 0; c < 3; ++c) {
            float xr = x[n * 3 + c] - xs[b * 3 + c] / cc;
            atomicAdd(&out[b * 3 + c], qn * xr);
        }
    }
}

// ---------------- launch ----------------
extern "C" void kernel_launch(void* const* d_in, const int* in_sizes, int n_in,
                              void* d_out, int out_size, void* d_ws, size_t ws_size,
                              hipStream_t stream) {
    const int* z = (const int*)d_in[0];
    const float* pos = (const float*)d_in[1];
    const int* ei0 = (const int*)d_in[2];
    const int* ei1 = ei0 + Ee;
    const int* batch = (const int*)d_in[3];
    const float* emb = (const float*)d_in[4];
    const float* eW1 = (const float*)d_in[5];
    const float* eb1 = (const float*)d_in[6];
    const float* eW2 = (const float*)d_in[7];
    const float* eb2 = (const float*)d_in[8];
    const float* cW = (const float*)d_in[9];
    const float* cb = (const float*)d_in[10];
    const float* nW1 = (const float*)d_in[11];
    const float* nb1 = (const float*)d_in[12];
    const float* nW2 = (const float*)d_in[13];
    const float* nb2 = (const float*)d_in[14];
    const float* qW1 = (const float*)d_in[15];
    const float* qb1 = (const float*)d_in[16];
    const float* qW2 = (const float*)d_in[17];
    const float* qb2 = (const float*)d_in[18];

    char* ws = (char*)d_ws;
    size_t o = 0;
    auto alloc = [&](size_t bytes) {
        size_t r = o;
        o = (o + bytes + 255) & ~(size_t)255;
        return r;
    };
    float* h = (float*)(ws + alloc((size_t)Nn * 64 * 4));
    float* xp = (float*)(ws + alloc((size_t)Nn * 3 * 4));
    float* magg = (float*)(ws + alloc((size_t)Nn * 64 * 4));
    float* xacc = (float*)(ws + alloc((size_t)Nn * 3 * 4));
    size_t zero_span = (size_t)((char*)xacc - (char*)magg) + (size_t)Nn * 3 * 4;
    float* qv = (float*)(ws + alloc((size_t)Nn * 4));
    int* deg = (int*)(ws + alloc((size_t)Nn * 4));
    int* cur = (int*)(ws + alloc((size_t)Nn * 4));
    int* rows_s = (int*)(ws + alloc((size_t)Ee * 4));
    int* cols_s = (int*)(ws + alloc((size_t)Ee * 4));
    float* cnt = (float*)(ws + alloc((size_t)Bb * 4));
    float* xs = (float*)(ws + alloc((size_t)Bb * 3 * 4));
    bf16* hbm = (bf16*)(ws + alloc((size_t)Nn * 64 * 2));
    bf16* Pa = (bf16*)(ws + alloc((size_t)Nn * 64 * 2));
    bf16* Pb = (bf16*)(ws + alloc((size_t)Nn * 64 * 2));
    bf16* pw1 = (bf16*)(ws + alloc((size_t)4 * 8192 * 2));
    bf16* pw2 = (bf16*)(ws + alloc((size_t)4 * 4096 * 2));
    bf16* pn1 = (bf16*)(ws + alloc((size_t)4 * 8192 * 2));
    bf16* pn2 = (bf16*)(ws + alloc((size_t)4 * 4096 * 2));
    bf16* pq1 = (bf16*)(ws + alloc((size_t)4096 * 2));
    int* bsum = (int*)(ws + alloc((size_t)NB * 4));
    int* boff = (int*)(ws + alloc((size_t)NB * 4));

    hipMemsetAsync(deg, 0, (size_t)Nn * 4, stream);
    hipMemsetAsync(magg, 0, zero_span, stream);
    hipMemsetAsync(cnt, 0, (size_t)Bb * 4, stream);
    hipMemsetAsync(xs, 0, (size_t)Bb * 3 * 4, stream);
    hipMemsetAsync(d_out, 0, (size_t)out_size * 4, stream);

    hipMemcpyAsync(xp, pos, (size_t)Nn * 3 * 4, hipMemcpyDeviceToDevice, stream);
    k_setup<<<2048, 256, 0, stream>>>(h, hbm, z, emb, eW1, eW2, nW1, nW2, qW1,
                                      pw1, pw2, pn1, pn2, pq1, ei0, deg);
    k_scan1<<<NB, 256, 0, stream>>>(deg, bsum);
    k_scan2<<<1, 256, 0, stream>>>(bsum, boff);
    k_scan3<<<NB, 256, 0, stream>>>(deg, boff, cur, rows_s);
    k_scatter<<<(Ee + 255) / 256, 256, 0, stream>>>(ei0, ei1, cur, cols_s);

    k_proj<<<782, 256, 0, stream>>>(hbm, pw1, eb1, Pa, Pb);
    for (int l = 0; l < 4; ++l) {
        k_edge<<<6250, 256, 0, stream>>>(rows_s, cols_s, Pa, Pb, xp,
                                         pw2 + (size_t)l * 4096,
                                         eW1 + (size_t)l * 129 * 64,
                                         eb2 + l * 64,
                                         cW + l * 64, cb + l, magg, xacc);
        int nx = (l < 3) ? (l + 1) : 0;
        k_node<<<782, 256, 0, stream>>>(magg, xacc,
                                        pn1 + (size_t)l * 8192, pn2 + (size_t)l * 4096,
                                        nb1 + l * 64, nb2 + l * 64,
                                        h, hbm, xp,
                                        pw1 + (size_t)nx * 8192, eb1 + nx * 64,
                                        Pa, Pb, (l < 3) ? 1 : 0);
    }
    k_q<<<(Nn + 63) / 64, 256, 0, stream>>>(hbm, pq1, qb1, qW2, qb2, qv,
                                            batch, xp, cnt, xs);
    k_mu<<<(Nn + 255) / 256, 256, 0, stream>>>(batch, xp, qv, cnt, xs, (float*)d_out);
}

// Round 22
// 937.611 us; speedup vs baseline: 1.4247x; 1.0377x over previous
//
#include <hip/hip_runtime.h>
#include <math.h>

#define Nn 50000
#define Ee 1600000
#define Bb 512
#define TE 64
#define NTILES (Ee / TE)
#define NB ((Nn + 255) / 256)

typedef __bf16 bf16;
typedef __bf16 bf16x8 __attribute__((ext_vector_type(8)));
typedef __bf16 bf16x4 __attribute__((ext_vector_type(4)));
typedef float f32x4 __attribute__((ext_vector_type(4)));

__device__ __forceinline__ float silu_f(float v) {
    return v * __builtin_amdgcn_rcpf(1.f + __expf(-v));
}
__device__ __forceinline__ float tanh_f(float x) {
    float e = __expf(2.f * x);
    return 1.f - 2.f * __builtin_amdgcn_rcpf(e + 1.f);
}
__device__ __forceinline__ int pack2bf(float a, float b) {
    unsigned short ua = __builtin_bit_cast(unsigned short, (bf16)a);
    unsigned short ub = __builtin_bit_cast(unsigned short, (bf16)b);
    return (int)ua | ((int)ub << 16);
}
__device__ __forceinline__ float unlo(int v) {
    return __builtin_bit_cast(float, v << 16);
}
__device__ __forceinline__ float unhi(int v) {
    return __builtin_bit_cast(float, v & 0xffff0000);
}

// ---------------- weight packing into MFMA A-fragment order ----------------
__device__ __forceinline__ void packfrag(bf16* dst, const float* src, int idx) {
    int j = idx & 7, lane = (idx >> 3) & 63, gT = idx >> 9;
    int kc = gT >> 2, T = gT & 3;
    int k = kc * 32 + (lane >> 4) * 8 + j;
    int n = T * 16 + (lane & 15);
    dst[idx] = (bf16)src[k * 64 + n];
}

// fused setup: h=emb[z] (fp32+bf16), weight packing, degree histogram (independent jobs)
#define SETUP_TOT (Nn * 64 + 102400 + Ee)
__global__ void k_setup(float* __restrict__ h, bf16* __restrict__ hb,
                        const int* __restrict__ z, const float* __restrict__ emb,
                        const float* __restrict__ eW1, const float* __restrict__ eW2,
                        const float* __restrict__ nW1, const float* __restrict__ nW2,
                        const float* __restrict__ qW1,
                        bf16* __restrict__ pw1, bf16* __restrict__ pw2,
                        bf16* __restrict__ pn1, bf16* __restrict__ pn2,
                        bf16* __restrict__ pq1,
                        const int* __restrict__ rows, int* __restrict__ deg) {
    for (int i = blockIdx.x * blockDim.x + threadIdx.x; i < SETUP_TOT;
         i += gridDim.x * blockDim.x) {
        if (i < Nn * 64) {
            int n = i >> 6, f = i & 63;
            float v = emb[z[n] * 64 + f];
            h[i] = v;
            hb[i] = (bf16)v;
        } else if (i < Nn * 64 + 102400) {
            int tid = i - Nn * 64;
            if (tid < 32768) {
                int l = tid >> 13, idx = tid & 8191;
                packfrag(pw1 + l * 8192, eW1 + (size_t)l * 129 * 64, idx);
            } else if (tid < 49152) {
                int k = tid - 32768, l = k >> 12, idx = k & 4095;
                packfrag(pw2 + l * 4096, eW2 + (size_t)l * 4096, idx);
            } else if (tid < 81920) {
                int k = tid - 49152, l = k >> 13, idx = k & 8191;
                packfrag(pn1 + l * 8192, nW1 + (size_t)l * 8192, idx);
            } else if (tid < 98304) {
                int k = tid - 81920, l = k >> 12, idx = k & 4095;
                packfrag(pn2 + l * 4096, nW2 + (size_t)l * 4096, idx);
            } else {
                packfrag(pq1, qW1, tid - 98304);
            }
        } else {
            int e = i - Nn * 64 - 102400;
            atomicAdd(&deg[rows[e]], 1);
        }
    }
}

__global__ void k_scan1(const int* __restrict__ deg, int* __restrict__ bsum) {
    __shared__ int red[4];
    int b = blockIdx.x;
    int i = b * 256 + threadIdx.x;
    int v = (i < Nn) ? deg[i] : 0;
#pragma unroll
    for (int off = 1; off < 64; off <<= 1) v += __shfl_xor(v, off);
    if ((threadIdx.x & 63) == 0) red[threadIdx.x >> 6] = v;
    __syncthreads();
    if (threadIdx.x == 0) bsum[b] = red[0] + red[1] + red[2] + red[3];
}

__global__ void k_scan2(const int* __restrict__ bsum, int* __restrict__ boff) {
    __shared__ int s[256];
    int t = threadIdx.x;
    int v = (t < NB) ? bsum[t] : 0;
    s[t] = v;
    __syncthreads();
    for (int off = 1; off < 256; off <<= 1) {
        int u = (t >= off) ? s[t - off] : 0;
        __syncthreads();
        s[t] += u;
        __syncthreads();
    }
    if (t < NB) boff[t] = s[t] - v;
}

// fused: exclusive scan -> cur (scatter cursor) + rows_s expansion
__global__ void k_scan3(const int* __restrict__ deg, const int* __restrict__ boff,
                        int* __restrict__ cur, int* __restrict__ rows_s) {
    __shared__ int s[256];
    int b = blockIdx.x, t = threadIdx.x;
    int i = b * 256 + t;
    int v = (i < Nn) ? deg[i] : 0;
    s[t] = v;
    __syncthreads();
    for (int off = 1; off < 256; off <<= 1) {
        int u = (t >= off) ? s[t - off] : 0;
        __syncthreads();
        s[t] += u;
        __syncthreads();
    }
    if (i < Nn) {
        int en = boff[b] + s[t];
        int st = en - v;
        cur[i] = st;
        for (int o = st; o < en; ++o) rows_s[o] = i;
    }
}

// cols-only scatter; cur holds absolute offsets
__global__ void k_scatter(const int* __restrict__ rows, const int* __restrict__ cols,
                          int* __restrict__ cur, int* __restrict__ cols_s) {
    int e = blockIdx.x * blockDim.x + threadIdx.x;
    if (e < Ee) {
        int o = atomicAdd(&cur[rows[e]], 1);
        cols_s[o] = cols[e];
    }
}

// ---------------- layer-0 node projection: Pa = H@W1a + b1, Pb = H@W1b (bf16 out) ----------------
__global__ __launch_bounds__(256) void k_proj(
    const bf16* __restrict__ hbuf, const bf16* __restrict__ pw1l,
    const float* __restrict__ b1v,
    bf16* __restrict__ Pa, bf16* __restrict__ Pb) {
    __shared__ __align__(16) bf16 inB[8 * 64 * 8];
    __shared__ float dhT[64 * 65];
    __shared__ __align__(16) float sb1[64];

    const int t = threadIdx.x;
    const int l = t & 63, w = t >> 6, q = l >> 4, nl = l & 15;
    const int fq = 4 * q;
    const int ge = t >> 2, part = t & 3;

    bf16x8 w1f[4][4];
#pragma unroll
    for (int kc = 0; kc < 4; ++kc)
#pragma unroll
        for (int T = 0; T < 4; ++T)
            w1f[kc][T] = *(const bf16x8*)(pw1l + (((kc * 4 + T) * 64 + l) << 3));
    if (t < 64) sb1[t] = b1v[t];

    const int NT = (Nn + 63) / 64;
    for (int bt = blockIdx.x; bt < NT; bt += gridDim.x) {
        const int base = bt * 64;
        __syncthreads();
        {
            int n = base + ge;
            if (n < Nn) {
                const bf16* hr = hbuf + ((size_t)n << 6) + part * 16;
                *(bf16x8*)&inB[(((part * 2 + 0) * 64) + ge) << 3] = *(const bf16x8*)(hr);
                *(bf16x8*)&inB[(((part * 2 + 1) * 64) + ge) << 3] = *(const bf16x8*)(hr + 8);
            } else {
                bf16x8 zz = {(bf16)0.f, (bf16)0.f, (bf16)0.f, (bf16)0.f,
                             (bf16)0.f, (bf16)0.f, (bf16)0.f, (bf16)0.f};
                *(bf16x8*)&inB[(((part * 2 + 0) * 64) + ge) << 3] = zz;
                *(bf16x8*)&inB[(((part * 2 + 1) * 64) + ge) << 3] = zz;
            }
        }
        __syncthreads();

        f32x4 apa[4], apb[4];
#pragma unroll
        for (int T = 0; T < 4; ++T) {
            apa[T] = (f32x4){0.f, 0.f, 0.f, 0.f};
            apb[T] = (f32x4){0.f, 0.f, 0.f, 0.f};
        }
#pragma unroll
        for (int kc = 0; kc < 2; ++kc) {
            bf16x8 bfrag = *(const bf16x8*)&inB[(((kc * 4 + q) * 64) + w * 16 + nl) << 3];
#pragma unroll
            for (int T = 0; T < 4; ++T) {
                apa[T] = __builtin_amdgcn_mfma_f32_16x16x32_bf16(w1f[kc][T], bfrag, apa[T], 0, 0, 0);
                apb[T] = __builtin_amdgcn_mfma_f32_16x16x32_bf16(w1f[kc + 2][T], bfrag, apb[T], 0, 0, 0);
            }
        }
#pragma unroll
        for (int T = 0; T < 4; ++T) {
#pragma unroll
            for (int r = 0; r < 4; ++r)
                dhT[(T * 16 + fq + r) * 65 + w * 16 + nl] = apa[T][r] + sb1[T * 16 + fq + r];
        }
        __syncthreads();
        {
            int n = base + ge;
            if (n < Nn) {
#pragma unroll
                for (int j = 0; j < 4; ++j) {
                    int f = part * 16 + j * 4;
                    bf16x4 bv = {(bf16)dhT[(f + 0) * 65 + ge], (bf16)dhT[(f + 1) * 65 + ge],
                                 (bf16)dhT[(f + 2) * 65 + ge], (bf16)dhT[(f + 3) * 65 + ge]};
                    *(bf16x4*)(Pa + ((size_t)n << 6) + f) = bv;
                }
            }
        }
        __syncthreads();
#pragma unroll
        for (int T = 0; T < 4; ++T) {
#pragma unroll
            for (int r = 0; r < 4; ++r)
                dhT[(T * 16 + fq + r) * 65 + w * 16 + nl] = apb[T][r];
        }
        __syncthreads();
        {
            int n = base + ge;
            if (n < Nn) {
#pragma unroll
                for (int j = 0; j < 4; ++j) {
                    int f = part * 16 + j * 4;
                    bf16x4 bv = {(bf16)dhT[(f + 0) * 65 + ge], (bf16)dhT[(f + 1) * 65 + ge],
                                 (bf16)dhT[(f + 2) * 65 + ge], (bf16)dhT[(f + 3) * 65 + ge]};
                    *(bf16x4*)(Pb + ((size_t)n << 6) + f) = bv;
                }
            }
        }
    }
}

// ---------------- edge kernel: gather bf16 Pa/Pb, fragment-native layout ----------------
// Thread (w, q, nl) owns edge eo+nl and B-fragment k-slots {c2*32 + q*8 + j}.
// 2-stage register pipeline RETRY at __launch_bounds__(256,4):
//   R8's pipeline at (256,8) spilled (64-VGPR cap -> FETCH 4x, dur +57%).
//   (256,4) raises the allocator budget to 128; expected usage ~48-64 VGPRs,
//   so NO spill and (since LDS caps blocks at 8 and usage<=64 keeps 8 waves/SIMD)
//   ideally NO occupancy loss. Falsifier: VGPR>64 / Occupancy drop / FETCH>>139MB.
// Base state for revert: (256,8) non-pipelined = 972.97 us total, k_edge 137 us.
__global__ __launch_bounds__(256, 4) void k_edge(
    const int* __restrict__ rows_s, const int* __restrict__ cols_s,
    const bf16* __restrict__ Pa, const bf16* __restrict__ Pb,
    const float* __restrict__ x,
    const bf16* __restrict__ pw2l,
    const float* __restrict__ w1f32,
    const float* __restrict__ b2v,
    const float* __restrict__ cwv, const float* __restrict__ cbv,
    float* __restrict__ m_agg, float* __restrict__ x_acc) {
    __shared__ __align__(16) bf16 lw2[4096];
    __shared__ __align__(16) float w128s[64], b2s[64], cws[64];
    __shared__ int mEp[32 * 65];
    __shared__ __align__(16) float relsm[64 * 4];
    __shared__ float coefs[64];
    __shared__ int srow[64];

    const int t = threadIdx.x;
    const int l = t & 63, w = t >> 6, q = l >> 4, nl = l & 15;
    const int fq = 4 * q;

    {
        const int4* s2 = (const int4*)pw2l;
        int4* d2p = (int4*)lw2;
#pragma unroll
        for (int i = 0; i < 2; ++i) d2p[t + 256 * i] = s2[t + 256 * i];
        if (t < 64) {
            w128s[t] = w1f32[128 * 64 + t];
            b2s[t] = b2v[t];
            cws[t] = cwv[t];
        }
    }
    const float cb0 = cbv[0];
    __syncthreads();

    // tile-invariant dist2-weight quads for this thread's k-slots (hoisted)
    const float4 w00 = *(const float4*)&w128s[q * 8 + 0];
    const float4 w01 = *(const float4*)&w128s[q * 8 + 4];
    const float4 w10 = *(const float4*)&w128s[32 + q * 8 + 0];
    const float4 w11 = *(const float4*)&w128s[32 + q * 8 + 4];

    const int gs = gridDim.x;

    // pipeline prologue: indices + gathers for the first tile
    int r_g, c_g;
    int4 A0, A1, B0, B1;
    {
        const int eg = blockIdx.x * TE + w * 16 + nl;
        r_g = rows_s[eg];
        c_g = cols_s[eg];
        const bf16* par = Pa + ((size_t)r_g << 6) + q * 8;
        const bf16* pbc = Pb + ((size_t)c_g << 6) + q * 8;
        A0 = *(const int4*)(par);
        A1 = *(const int4*)(par + 32);
        B0 = *(const int4*)(pbc);
        B1 = *(const int4*)(pbc + 32);
    }

    for (int tile = blockIdx.x; tile < NTILES; tile += gs) {
        // current tile geometry (indices already in registers)
        float rx = x[r_g * 3 + 0] - x[c_g * 3 + 0];
        float ry = x[r_g * 3 + 1] - x[c_g * 3 + 1];
        float rz = x[r_g * 3 + 2] - x[c_g * 3 + 2];
        float d2 = fmaf(rx, rx, fmaf(ry, ry, rz * rz));
        if (q == 0) {
            srow[w * 16 + nl] = r_g;
            float4 rv;
            rv.x = rx; rv.y = ry; rv.z = rz; rv.w = d2;
            *(float4*)&relsm[(w * 16 + nl) * 4] = rv;
        }

        // prefetch next tile's indices (issue early)
        const int nt = tile + gs;
        const int ntc = (nt < NTILES) ? nt : tile;
        const int eg2 = ntc * TE + w * 16 + nl;
        int r_n = rows_s[eg2];
        int c_n = cols_s[eg2];

        // silu + pack with current gathers (in registers since last iteration)
        union { int i[4]; bf16x8 v; } bu0, bu1;
        bu0.i[0] = pack2bf(silu_f(fmaf(w00.x, d2, unlo(A0.x) + unlo(B0.x))),
                           silu_f(fmaf(w00.y, d2, unhi(A0.x) + unhi(B0.x))));
        bu0.i[1] = pack2bf(silu_f(fmaf(w00.z, d2, unlo(A0.y) + unlo(B0.y))),
                           silu_f(fmaf(w00.w, d2, unhi(A0.y) + unhi(B0.y))));
        bu0.i[2] = pack2bf(silu_f(fmaf(w01.x, d2, unlo(A0.z) + unlo(B0.z))),
                           silu_f(fmaf(w01.y, d2, unhi(A0.z) + unhi(B0.z))));
        bu0.i[3] = pack2bf(silu_f(fmaf(w01.z, d2, unlo(A0.w) + unlo(B0.w))),
                           silu_f(fmaf(w01.w, d2, unhi(A0.w) + unhi(B0.w))));
        bu1.i[0] = pack2bf(silu_f(fmaf(w10.x, d2, unlo(A1.x) + unlo(B1.x))),
                           silu_f(fmaf(w10.y, d2, unhi(A1.x) + unhi(B1.x))));
        bu1.i[1] = pack2bf(silu_f(fmaf(w10.z, d2, unlo(A1.y) + unlo(B1.y))),
                           silu_f(fmaf(w10.w, d2, unhi(A1.y) + unhi(B1.y))));
        bu1.i[2] = pack2bf(silu_f(fmaf(w11.x, d2, unlo(A1.z) + unlo(B1.z))),
                           silu_f(fmaf(w11.y, d2, unhi(A1.z) + unhi(B1.z))));
        bu1.i[3] = pack2bf(silu_f(fmaf(w11.z, d2, unlo(A1.w) + unlo(B1.w))),
                           silu_f(fmaf(w11.w, d2, unhi(A1.w) + unhi(B1.w))));

        // prefetch next tile's Pa/Pb gathers; latency hides under MFMA+reduction
        {
            const bf16* parn = Pa + ((size_t)r_n << 6) + q * 8;
            const bf16* pbcn = Pb + ((size_t)c_n << 6) + q * 8;
            A0 = *(const int4*)(parn);
            A1 = *(const int4*)(parn + 32);
            B0 = *(const int4*)(pbcn);
            B1 = *(const int4*)(pbcn + 32);
        }

        f32x4 a2[4];
#pragma unroll
        for (int T = 0; T < 4; ++T) a2[T] = (f32x4){0.f, 0.f, 0.f, 0.f};
#pragma unroll
        for (int T = 0; T < 4; ++T) {
            bf16x8 wf = *(const bf16x8*)&lw2[(((0 * 4 + T) * 64) + l) << 3];
            a2[T] = __builtin_amdgcn_mfma_f32_16x16x32_bf16(wf, bu0.v, a2[T], 0, 0, 0);
        }
#pragma unroll
        for (int T = 0; T < 4; ++T) {
            bf16x8 wf = *(const bf16x8*)&lw2[(((1 * 4 + T) * 64) + l) << 3];
            a2[T] = __builtin_amdgcn_mfma_f32_16x16x32_bf16(wf, bu1.v, a2[T], 0, 0, 0);
        }
        float pc = 0.f;
#pragma unroll
        for (int T = 0; T < 4; ++T) {
            const float4 bq = *(const float4*)&b2s[T * 16 + fq];
            const float4 cq = *(const float4*)&cws[T * 16 + fq];
            float m0 = silu_f(a2[T][0] + bq.x);
            float m1 = silu_f(a2[T][1] + bq.y);
            float m2 = silu_f(a2[T][2] + bq.z);
            float m3 = silu_f(a2[T][3] + bq.w);
            int p0 = (T * 16 + fq) >> 1;
            mEp[(p0 + 0) * 65 + w * 16 + nl] = pack2bf(m0, m1);
            mEp[(p0 + 1) * 65 + w * 16 + nl] = pack2bf(m2, m3);
            pc += m0 * cq.x + m1 * cq.y + m2 * cq.z + m3 * cq.w;
        }
        pc += __shfl_xor(pc, 16);
        pc += __shfl_xor(pc, 32);
        if (q == 0) coefs[w * 16 + nl] = tanh_f(pc + cb0);
        __syncthreads();  // barrier A

        {
            int rl = srow[l];
            int rprev = __shfl(rl, l - 1);
            bool isst = (l == 0) || (rl != rprev);
            unsigned long long mask = __ballot(isst);
            const int pair = l & 31, half = l >> 5;
            unsigned long long mm = mask;
            int s = 0;
            while (mm) {
                int st = __ffsll(mm) - 1;
                mm &= mm - 1;
                if ((s & 3) == w) {
                    int en = mm ? (__ffsll(mm) - 1) : TE;
                    int row = __shfl(rl, st);
                    float s0 = 0.f, s1 = 0.f, sx = 0.f;
                    for (int e = st + half; e < en; e += 2) {
                        int pv = mEp[pair * 65 + e];
                        s0 += __builtin_bit_cast(float, pv << 16);
                        s1 += __builtin_bit_cast(float, pv & 0xffff0000);
                    }
                    if (half == 1 && pair < 3) {
                        for (int e = st; e < en; ++e)
                            sx += relsm[e * 4 + pair] * coefs[e];
                    }
                    s0 += __shfl_xor(s0, 32);
                    s1 += __shfl_xor(s1, 32);
                    if (half == 0) {
                        atomicAdd(m_agg + (size_t)row * 64 + 2 * pair, s0);
                        atomicAdd(m_agg + (size_t)row * 64 + 2 * pair + 1, s1);
                    } else if (pair < 3) {
                        atomicAdd(x_acc + (size_t)row * 3 + pair, sx);
                    }
                }
                s++;
            }
        }
        __syncthreads();  // barrier B

        // rotate pipeline registers
        r_g = r_n;
        c_g = c_n;
    }
}

// ---------------- node kernel (MFMA, grid-stride; fused next-layer projection; zeroes accumulators) ----------------
__global__ __launch_bounds__(256) void k_node(
    float* __restrict__ m_agg, float* __restrict__ x_acc,
    const bf16* __restrict__ pn1l, const bf16* __restrict__ pn2l,
    const float* __restrict__ b1v, const float* __restrict__ b2v,
    float* __restrict__ h, bf16* __restrict__ hbuf, float* __restrict__ x,
    const bf16* __restrict__ pw1n, const float* __restrict__ b1n,
    bf16* __restrict__ Pa, bf16* __restrict__ Pb, int donext) {
    __shared__ __align__(16) bf16 inB[16 * 64 * 8];
    __shared__ float dhT[64 * 65];
    __shared__ __align__(16) float sb1[64], sb2[64], sb1n[64];

    const int t = threadIdx.x;
    const int l = t & 63, w = t >> 6, q = l >> 4, nl = l & 15;
    const int qh = q >> 1, qb = 2 * (q & 1), fq = 4 * q;
    const int ge = t >> 2, part = t & 3;

    bf16x8 w1f[4][4];
#pragma unroll
    for (int kc = 0; kc < 4; ++kc)
#pragma unroll
        for (int T = 0; T < 4; ++T)
            w1f[kc][T] = *(const bf16x8*)(pn1l + (((kc * 4 + T) * 64 + l) << 3));
    bf16x8 w2f[2][4];
#pragma unroll
    for (int c = 0; c < 2; ++c)
#pragma unroll
        for (int T = 0; T < 4; ++T)
            w2f[c][T] = *(const bf16x8*)(pn2l + (((c * 4 + T) * 64 + l) << 3));
    if (t < 64) { sb1[t] = b1v[t]; sb2[t] = b2v[t]; sb1n[t] = b1n[t]; }

    const int NT = (Nn + 63) / 64;
    for (int bt = blockIdx.x; bt < NT; bt += gridDim.x) {
        const int base = bt * 64;
        const int n_g = base + ge;
        __syncthreads();
        {
            if (n_g < Nn) {
                const bf16* hr = hbuf + ((size_t)n_g << 6) + part * 16;
                *(bf16x8*)&inB[(((part * 2 + 0) * 64) + ge) << 3] = *(const bf16x8*)(hr);
                *(bf16x8*)&inB[(((part * 2 + 1) * 64) + ge) << 3] = *(const bf16x8*)(hr + 8);
                float* mr = m_agg + ((size_t)n_g << 6) + part * 16;
                float4 m0 = *(const float4*)(mr + 0);
                float4 m1 = *(const float4*)(mr + 4);
                float4 m2 = *(const float4*)(mr + 8);
                float4 m3 = *(const float4*)(mr + 12);
                float4 z4 = {0.f, 0.f, 0.f, 0.f};
                *(float4*)(mr + 0) = z4;
                *(float4*)(mr + 4) = z4;
                *(float4*)(mr + 8) = z4;
                *(float4*)(mr + 12) = z4;
                bf16x8 bm0 = {(bf16)m0.x, (bf16)m0.y, (bf16)m0.z, (bf16)m0.w,
                              (bf16)m1.x, (bf16)m1.y, (bf16)m1.z, (bf16)m1.w};
                bf16x8 bm1 = {(bf16)m2.x, (bf16)m2.y, (bf16)m2.z, (bf16)m2.w,
                              (bf16)m3.x, (bf16)m3.y, (bf16)m3.z, (bf16)m3.w};
                *(bf16x8*)&inB[(((8 + part * 2 + 0) * 64) + ge) << 3] = bm0;
                *(bf16x8*)&inB[(((8 + part * 2 + 1) * 64) + ge) << 3] = bm1;
            } else {
                bf16x8 zz = {(bf16)0.f, (bf16)0.f, (bf16)0.f, (bf16)0.f,
                             (bf16)0.f, (bf16)0.f, (bf16)0.f, (bf16)0.f};
                *(bf16x8*)&inB[(((part * 2 + 0) * 64) + ge) << 3] = zz;
                *(bf16x8*)&inB[(((part * 2 + 1) * 64) + ge) << 3] = zz;
                *(bf16x8*)&inB[(((8 + part * 2 + 0) * 64) + ge) << 3] = zz;
                *(bf16x8*)&inB[(((8 + part * 2 + 1) * 64) + ge) << 3] = zz;
            }
        }
        __syncthreads();

        f32x4 a1[4];
#pragma unroll
        for (int T = 0; T < 4; ++T) a1[T] = (f32x4){0.f, 0.f, 0.f, 0.f};
#pragma unroll
        for (int kc = 0; kc < 4; ++kc) {
            bf16x8 bfrag = *(const bf16x8*)&inB[(((kc * 4 + q) * 64) + w * 16 + nl) << 3];
#pragma unroll
            for (int T = 0; T < 4; ++T)
                a1[T] = __builtin_amdgcn_mfma_f32_16x16x32_bf16(w1f[kc][T], bfrag, a1[T], 0, 0, 0);
        }
        int pk[4][2];
#pragma unroll
        for (int T = 0; T < 4; ++T) {
            const float4 bq = *(const float4*)&sb1[T * 16 + fq];
            float h0 = silu_f(a1[T][0] + bq.x);
            float h1 = silu_f(a1[T][1] + bq.y);
            float h2 = silu_f(a1[T][2] + bq.z);
            float h3 = silu_f(a1[T][3] + bq.w);
            pk[T][0] = pack2bf(h0, h1);
            pk[T][1] = pack2bf(h2, h3);
        }
        f32x4 a2[4];
#pragma unroll
        for (int T = 0; T < 4; ++T) a2[T] = (f32x4){0.f, 0.f, 0.f, 0.f};
#pragma unroll
        for (int c = 0; c < 2; ++c) {
            union { int i[4]; bf16x8 v; } bu;
#pragma unroll
            for (int d = 0; d < 4; ++d) {
                int src = (qb + (d >> 1)) * 16 + nl;
                int t0 = __shfl(pk[2 * c][d & 1], src);
                int t1 = __shfl(pk[2 * c + 1][d & 1], src);
                bu.i[d] = qh ? t1 : t0;
            }
#pragma unroll
            for (int T = 0; T < 4; ++T)
                a2[T] = __builtin_amdgcn_mfma_f32_16x16x32_bf16(w2f[c][T], bu.v, a2[T], 0, 0, 0);
        }
#pragma unroll
        for (int T = 0; T < 4; ++T) {
            const float4 bq = *(const float4*)&sb2[T * 16 + fq];
            dhT[(T * 16 + fq + 0) * 65 + w * 16 + nl] = a2[T][0] + bq.x;
            dhT[(T * 16 + fq + 1) * 65 + w * 16 + nl] = a2[T][1] + bq.y;
            dhT[(T * 16 + fq + 2) * 65 + w * 16 + nl] = a2[T][2] + bq.z;
            dhT[(T * 16 + fq + 3) * 65 + w * 16 + nl] = a2[T][3] + bq.w;
        }
        __syncthreads();
        {
            if (n_g < Nn) {
                bf16x4 hv[4];
#pragma unroll
                for (int j = 0; j < 4; ++j) {
                    int f = part * 16 + j * 4;
                    float4* hp = (float4*)(h + ((size_t)n_g << 6) + f);
                    float4 old = *hp;
                    old.x += dhT[(f + 0) * 65 + ge];
                    old.y += dhT[(f + 1) * 65 + ge];
                    old.z += dhT[(f + 2) * 65 + ge];
                    old.w += dhT[(f + 3) * 65 + ge];
                    *hp = old;
                    hv[j] = (bf16x4){(bf16)old.x, (bf16)old.y, (bf16)old.z, (bf16)old.w};
                    *(bf16x4*)(hbuf + ((size_t)n_g << 6) + f) = hv[j];
                }
                if (donext) {
                    union { bf16x4 h2[2]; bf16x8 v; } u0, u1;
                    u0.h2[0] = hv[0]; u0.h2[1] = hv[1];
                    u1.h2[0] = hv[2]; u1.h2[1] = hv[3];
                    *(bf16x8*)&inB[(((part * 2 + 0) * 64) + ge) << 3] = u0.v;
                    *(bf16x8*)&inB[(((part * 2 + 1) * 64) + ge) << 3] = u1.v;
                }
            } else if (donext) {
                bf16x8 zz = {(bf16)0.f, (bf16)0.f, (bf16)0.f, (bf16)0.f,
                             (bf16)0.f, (bf16)0.f, (bf16)0.f, (bf16)0.f};
                *(bf16x8*)&inB[(((part * 2 + 0) * 64) + ge) << 3] = zz;
                *(bf16x8*)&inB[(((part * 2 + 1) * 64) + ge) << 3] = zz;
            }
        }
        if (t < 64) {
            int n = base + t;
            if (n < Nn) {
#pragma unroll
                for (int c = 0; c < 3; ++c) {
                    x[n * 3 + c] += x_acc[n * 3 + c];
                    x_acc[n * 3 + c] = 0.f;
                }
            }
        }
        if (!donext) continue;
        __syncthreads();
        f32x4 apa[4], apb[4];
#pragma unroll
        for (int T = 0; T < 4; ++T) {
            apa[T] = (f32x4){0.f, 0.f, 0.f, 0.f};
            apb[T] = (f32x4){0.f, 0.f, 0.f, 0.f};
        }
#pragma unroll
        for (int kc = 0; kc < 2; ++kc) {
            bf16x8 bfrag = *(const bf16x8*)&inB[(((kc * 4 + q) * 64) + w * 16 + nl) << 3];
#pragma unroll
            for (int T = 0; T < 4; ++T) {
                bf16x8 wa = *(const bf16x8*)(pw1n + (((kc * 4 + T) * 64 + l) << 3));
                bf16x8 wb = *(const bf16x8*)(pw1n + ((((kc + 2) * 4 + T) * 64 + l) << 3));
                apa[T] = __builtin_amdgcn_mfma_f32_16x16x32_bf16(wa, bfrag, apa[T], 0, 0, 0);
                apb[T] = __builtin_amdgcn_mfma_f32_16x16x32_bf16(wb, bfrag, apb[T], 0, 0, 0);
            }
        }
#pragma unroll
        for (int T = 0; T < 4; ++T) {
#pragma unroll
            for (int r = 0; r < 4; ++r)
                dhT[(T * 16 + fq + r) * 65 + w * 16 + nl] = apa[T][r] + sb1n[T * 16 + fq + r];
        }
        __syncthreads();
        if (n_g < Nn) {
#pragma unroll
            for (int j = 0; j < 4; ++j) {
                int f = part * 16 + j * 4;
                bf16x4 bv = {(bf16)dhT[(f + 0) * 65 + ge], (bf16)dhT[(f + 1) * 65 + ge],
                             (bf16)dhT[(f + 2) * 65 + ge], (bf16)dhT[(f + 3) * 65 + ge]};
                *(bf16x4*)(Pa + ((size_t)n_g << 6) + f) = bv;
            }
        }
        __syncthreads();
#pragma unroll
        for (int T = 0; T < 4; ++T) {
#pragma unroll
            for (int r = 0; r < 4; ++r)
                dhT[(T * 16 + fq + r) * 65 + w * 16 + nl] = apb[T][r];
        }
        __syncthreads();
        if (n_g < Nn) {
#pragma unroll
            for (int j = 0; j < 4; ++j) {
                int f = part * 16 + j * 4;
                bf16x4 bv = {(bf16)dhT[(f + 0) * 65 + ge], (bf16)dhT[(f + 1) * 65 + ge],
                             (bf16)dhT[(f + 2) * 65 + ge], (bf16)dhT[(f + 3) * 65 + ge]};
                *(bf16x4*)(Pb + ((size_t)n_g << 6) + f) = bv;
            }
        }
    }
}

// ---------------- readout q (MFMA) + batch stats fused ----------------
__global__ __launch_bounds__(256) void k_q(
    const bf16* __restrict__ hbuf, const bf16* __restrict__ pq1,
    const float* __restrict__ b1v, const float* __restrict__ w2v,
    const float* __restrict__ b2v, float* __restrict__ qout,
    const int* __restrict__ batch, const float* __restrict__ x,
    float* __restrict__ cnt, float* __restrict__ xs) {
    __shared__ __align__(16) bf16 inB[8 * 64 * 8];
    __shared__ __align__(16) float sb1[64], sw2[64];
    const int t = threadIdx.x;
    const int l = t & 63, w = t >> 6, q = l >> 4, nl = l & 15;
    const int fq = 4 * q;
    const int ge = t >> 2, part = t & 3;

    bf16x8 w1f[2][4];
#pragma unroll
    for (int kc = 0; kc < 2; ++kc)
#pragma unroll
        for (int T = 0; T < 4; ++T)
            w1f[kc][T] = *(const bf16x8*)(pq1 + (((kc * 4 + T) * 64 + l) << 3));
    if (t < 64) { sb1[t] = b1v[t]; sw2[t] = w2v[t]; }
    const float qb2 = b2v[0];

    const int base = blockIdx.x * 64;
    if (t < 64) {
        int n = base + t;
        if (n < Nn) {
            int b = batch[n];
            atomicAdd(&cnt[b], 1.f);
            atomicAdd(&xs[b * 3 + 0], x[n * 3 + 0]);
            atomicAdd(&xs[b * 3 + 1], x[n * 3 + 1]);
            atomicAdd(&xs[b * 3 + 2], x[n * 3 + 2]);
        }
    }
    {
        int n = base + ge;
        if (n < Nn) {
            const bf16* hr = hbuf + ((size_t)n << 6) + part * 16;
            *(bf16x8*)&inB[(((part * 2 + 0) * 64) + ge) << 3] = *(const bf16x8*)(hr);
            *(bf16x8*)&inB[(((part * 2 + 1) * 64) + ge) << 3] = *(const bf16x8*)(hr + 8);
        } else {
            bf16x8 zz = {(bf16)0.f, (bf16)0.f, (bf16)0.f, (bf16)0.f,
                         (bf16)0.f, (bf16)0.f, (bf16)0.f, (bf16)0.f};
            *(bf16x8*)&inB[(((part * 2 + 0) * 64) + ge) << 3] = zz;
            *(bf16x8*)&inB[(((part * 2 + 1) * 64) + ge) << 3] = zz;
        }
    }
    __syncthreads();
    f32x4 a1[4];
#pragma unroll
    for (int T = 0; T < 4; ++T) a1[T] = (f32x4){0.f, 0.f, 0.f, 0.f};
#pragma unroll
    for (int kc = 0; kc < 2; ++kc) {
        bf16x8 bfrag = *(const bf16x8*)&inB[(((kc * 4 + q) * 64) + w * 16 + nl) << 3];
#pragma unroll
        for (int T = 0; T < 4; ++T)
            a1[T] = __builtin_amdgcn_mfma_f32_16x16x32_bf16(w1f[kc][T], bfrag, a1[T], 0, 0, 0);
    }
    float pc = 0.f;
#pragma unroll
    for (int T = 0; T < 4; ++T) {
        const float4 bq = *(const float4*)&sb1[T * 16 + fq];
        const float4 cq = *(const float4*)&sw2[T * 16 + fq];
        pc += silu_f(a1[T][0] + bq.x) * cq.x;
        pc += silu_f(a1[T][1] + bq.y) * cq.y;
        pc += silu_f(a1[T][2] + bq.z) * cq.z;
        pc += silu_f(a1[T][3] + bq.w) * cq.w;
    }
    pc += __shfl_xor(pc, 16);
    pc += __shfl_xor(pc, 32);
    if (q == 0) {
        int n = base + w * 16 + nl;
        if (n < Nn) qout[n] = pc + qb2;
    }
}

__global__ void k_mu(const int* __restrict__ batch, const float* __restrict__ x,
                     const float* __restrict__ q, const float* __restrict__ cnt,
                     const float* __restrict__ xs, float* __restrict__ out) {
    int n = blockIdx.x * blockDim.x + threadIdx.x;
    if (n < Nn) {
        int b = batch[n];
        float cc = fmaxf(cnt[b], 1.f);
        float qn = q[n];
#pragma unroll
        for (int c = 0; c < 3; ++c) {
            float xr = x[n * 3 + c] - xs[b * 3 + c] / cc;
            atomicAdd(&out[b * 3 + c], qn * xr);
        }
    }
}

// ---------------- launch ----------------
extern "C" void kernel_launch(void* const* d_in, const int* in_sizes, int n_in,
                              void* d_out, int out_size, void* d_ws, size_t ws_size,
                              hipStream_t stream) {
    const int* z = (const int*)d_in[0];
    const float* pos = (const float*)d_in[1];
    const int* ei0 = (const int*)d_in[2];
    const int* ei1 = ei0 + Ee;
    const int* batch = (const int*)d_in[3];
    const float* emb = (const float*)d_in[4];
    const float* eW1 = (const float*)d_in[5];
    const float* eb1 = (const float*)d_in[6];
    const float* eW2 = (const float*)d_in[7];
    const float* eb2 = (const float*)d_in[8];
    const float* cW = (const float*)d_in[9];
    const float* cb = (const float*)d_in[10];
    const float* nW1 = (const float*)d_in[11];
    const float* nb1 = (const float*)d_in[12];
    const float* nW2 = (const float*)d_in[13];
    const float* nb2 = (const float*)d_in[14];
    const float* qW1 = (const float*)d_in[15];
    const float* qb1 = (const float*)d_in[16];
    const float* qW2 = (const float*)d_in[17];
    const float* qb2 = (const float*)d_in[18];

    char* ws = (char*)d_ws;
    size_t o = 0;
    auto alloc = [&](size_t bytes) {
        size_t r = o;
        o = (o + bytes + 255) & ~(size_t)255;
        return r;
    };
    float* h = (float*)(ws + alloc((size_t)Nn * 64 * 4));
    float* xp = (float*)(ws + alloc((size_t)Nn * 3 * 4));
    float* magg = (float*)(ws + alloc((size_t)Nn * 64 * 4));
    float* xacc = (float*)(ws + alloc((size_t)Nn * 3 * 4));
    size_t zero_span = (size_t)((char*)xacc - (char*)magg) + (size_t)Nn * 3 * 4;
    float* qv = (float*)(ws + alloc((size_t)Nn * 4));
    int* deg = (int*)(ws + alloc((size_t)Nn * 4));
    int* cur = (int*)(ws + alloc((size_t)Nn * 4));
    int* rows_s = (int*)(ws + alloc((size_t)Ee * 4));
    int* cols_s = (int*)(ws + alloc((size_t)Ee * 4));
    float* cnt = (float*)(ws + alloc((size_t)Bb * 4));
    float* xs = (float*)(ws + alloc((size_t)Bb * 3 * 4));
    bf16* hbm = (bf16*)(ws + alloc((size_t)Nn * 64 * 2));
    bf16* Pa = (bf16*)(ws + alloc((size_t)Nn * 64 * 2));
    bf16* Pb = (bf16*)(ws + alloc((size_t)Nn * 64 * 2));
    bf16* pw1 = (bf16*)(ws + alloc((size_t)4 * 8192 * 2));
    bf16* pw2 = (bf16*)(ws + alloc((size_t)4 * 4096 * 2));
    bf16* pn1 = (bf16*)(ws + alloc((size_t)4 * 8192 * 2));
    bf16* pn2 = (bf16*)(ws + alloc((size_t)4 * 4096 * 2));
    bf16* pq1 = (bf16*)(ws + alloc((size_t)4096 * 2));
    int* bsum = (int*)(ws + alloc((size_t)NB * 4));
    int* boff = (int*)(ws + alloc((size_t)NB * 4));

    hipMemsetAsync(deg, 0, (size_t)Nn * 4, stream);
    hipMemsetAsync(magg, 0, zero_span, stream);
    hipMemsetAsync(cnt, 0, (size_t)Bb * 4, stream);
    hipMemsetAsync(xs, 0, (size_t)Bb * 3 * 4, stream);
    hipMemsetAsync(d_out, 0, (size_t)out_size * 4, stream);

    hipMemcpyAsync(xp, pos, (size_t)Nn * 3 * 4, hipMemcpyDeviceToDevice, stream);
    k_setup<<<2048, 256, 0, stream>>>(h, hbm, z, emb, eW1, eW2, nW1, nW2, qW1,
                                      pw1, pw2, pn1, pn2, pq1, ei0, deg);
    k_scan1<<<NB, 256, 0, stream>>>(deg, bsum);
    k_scan2<<<1, 256, 0, stream>>>(bsum, boff);
    k_scan3<<<NB, 256, 0, stream>>>(deg, boff, cur, rows_s);
    k_scatter<<<(Ee + 255) / 256, 256, 0, stream>>>(ei0, ei1, cur, cols_s);

    k_proj<<<782, 256, 0, stream>>>(hbm, pw1, eb1, Pa, Pb);
    for (int l = 0; l < 4; ++l) {
        k_edge<<<6250, 256, 0, stream>>>(rows_s, cols_s, Pa, Pb, xp,
                                         pw2 + (size_t)l * 4096,
                                         eW1 + (size_t)l * 129 * 64,
                                         eb2 + l * 64,
                                         cW + l * 64, cb + l, magg, xacc);
        int nx = (l < 3) ? (l + 1) : 0;
        k_node<<<782, 256, 0, stream>>>(magg, xacc,
                                        pn1 + (size_t)l * 8192, pn2 + (size_t)l * 4096,
                                        nb1 + l * 64, nb2 + l * 64,
                                        h, hbm, xp,
                                        pw1 + (size_t)nx * 8192, eb1 + nx * 64,
                                        Pa, Pb, (l < 3) ? 1 : 0);
    }
    k_q<<<(Nn + 63) / 64, 256, 0, stream>>>(hbm, pq1, qb1, qW2, qb2, qv,
                                            batch, xp, cnt, xs);
    k_mu<<<(Nn + 255) / 256, 256, 0, stream>>>(batch, xp, qv, cnt, xs, (float*)d_out);
}